// Round 2
// baseline (482.811 us; speedup 1.0000x reference)
//
#include <hip/hip_runtime.h>
#include <hip/hip_bf16.h>

#define N_NODES 50000
#define N_EDGES 800000
#define M_PAD   50048   // 391 * 128
#define NBLK    391

typedef __attribute__((ext_vector_type(8))) short bf16x8_t;
typedef __attribute__((ext_vector_type(4))) float f32x4_t;

__device__ __forceinline__ unsigned short f2bf(float f) {
    unsigned u = __float_as_uint(f);
    u += 0x7FFFu + ((u >> 16) & 1u);
    return (unsigned short)(u >> 16);
}
__device__ __forceinline__ float bf2f(unsigned short h) {
    return __uint_as_float(((unsigned)h) << 16);
}

// ---------------- small prep kernels ----------------

__global__ void zero_kernel(int* p, int n) {
    int i = blockIdx.x * 256 + threadIdx.x;
    if (i < n) p[i] = 0;
}

__global__ void convert_kernel(const float* __restrict__ X, const float* __restrict__ Hsrc,
                               unsigned short* __restrict__ Xb, unsigned short* __restrict__ Hb) {
    int i = blockIdx.x * 256 + threadIdx.x;          // quad index
    if (i >= N_NODES * 32) return;
    float4 x = ((const float4*)X)[i];
    float4 h = ((const float4*)Hsrc)[i];
    ushort4 a, b;
    a.x = f2bf(x.x); a.y = f2bf(x.y); a.z = f2bf(x.z); a.w = f2bf(x.w);
    b.x = f2bf(h.x); b.y = f2bf(h.y); b.z = f2bf(h.z); b.w = f2bf(h.w);
    ((ushort4*)Xb)[i] = a;
    ((ushort4*)Hb)[i] = b;
}

// Pack weights into MFMA B-fragment order.
// For matrix W[K][N] row-major: frag element j of lane l at (nt, ks) is
// W[ks*32 + 8*(l>>4) + j][nt*16 + (l&15)], stored contiguously 8 per lane.
__global__ void wfrag_kernel(const float* __restrict__ Wz, const float* __restrict__ Wr,
                             const float* __restrict__ Wh,
                             const float* __restrict__ Wlz, const float* __restrict__ Wlr,
                             const float* __restrict__ Wlh,
                             unsigned short* __restrict__ Wf, unsigned short* __restrict__ Wlf) {
    int tid = blockIdx.x * 256 + threadIdx.x;
    if (tid < 3 * 2048) {            // W_* : K=128 (4 ksteps), N=128 (8 ntiles)
        int m = tid / 2048, t = tid % 2048;
        int nt = t / 256, ks = (t / 64) % 4, lane = t % 64;
        const float* W = (m == 0) ? Wz : (m == 1) ? Wr : Wh;
        unsigned short* dst = Wf + m * 128 * 128 + ((nt * 4 + ks) * 64 + lane) * 8;
        int n = nt * 16 + (lane & 15);
        int k0 = ks * 32 + 8 * (lane >> 4);
        #pragma unroll
        for (int j = 0; j < 8; ++j) dst[j] = f2bf(W[(k0 + j) * 128 + n]);
    } else {
        int u = tid - 3 * 2048;
        if (u < 3 * 4096) {          // Wl_* : K=256 (8 ksteps), N=128
            int m = u / 4096, t = u % 4096;
            int nt = t / 512, ks = (t / 64) % 8, lane = t % 64;
            const float* W = (m == 0) ? Wlz : (m == 1) ? Wlr : Wlh;
            unsigned short* dst = Wlf + m * 256 * 128 + ((nt * 8 + ks) * 64 + lane) * 8;
            int n = nt * 16 + (lane & 15);
            int k0 = ks * 32 + 8 * (lane >> 4);
            #pragma unroll
            for (int j = 0; j < 8; ++j) dst[j] = f2bf(W[(k0 + j) * 128 + n]);
        }
    }
}

// ---------------- graph prep ----------------

__global__ void pass1_kernel(const int* __restrict__ EI, const float* __restrict__ EW,
                             float* __restrict__ deg, int* __restrict__ counts) {
    int i = blockIdx.x * 256 + threadIdx.x;
    if (i >= N_EDGES) return;
    int t = EI[N_EDGES + i];
    atomicAdd(&deg[t], EW[i]);
    atomicAdd(&counts[t], 1);
}

__global__ void node_kernel(const float* __restrict__ deg, float* __restrict__ dinv,
                            float* __restrict__ dinv2) {
    int i = blockIdx.x * 256 + threadIdx.x;
    if (i >= N_NODES) return;
    float d = deg[i] + 1.0f;
    float di = rsqrtf(d);
    dinv[i] = di;
    dinv2[i] = di * di;
}

__global__ void scan_kernel(const int* __restrict__ counts, int* __restrict__ offs,
                            int* __restrict__ cursor) {
    __shared__ int part[1024];
    int t = threadIdx.x;
    const int CH = (N_NODES + 1023) / 1024;   // 49
    int base = t * CH;
    int s = 0;
    for (int i = 0; i < CH; ++i) {
        int idx = base + i;
        if (idx < N_NODES) s += counts[idx];
    }
    part[t] = s;
    __syncthreads();
    for (int off = 1; off < 1024; off <<= 1) {
        int v = (t >= off) ? part[t - off] : 0;
        __syncthreads();
        part[t] += v;
        __syncthreads();
    }
    int run = (t == 0) ? 0 : part[t - 1];
    for (int i = 0; i < CH; ++i) {
        int idx = base + i;
        if (idx < N_NODES) { offs[idx] = run; cursor[idx] = run; run += counts[idx]; }
    }
    if (t == 1023) offs[N_NODES] = part[1023];
}

__global__ void fill_kernel(const int* __restrict__ EI, const float* __restrict__ EW,
                            const float* __restrict__ dinv, int* __restrict__ cursor,
                            int2* __restrict__ rec) {
    int i = blockIdx.x * 256 + threadIdx.x;
    if (i >= N_EDGES) return;
    int s = EI[i];
    int t = EI[N_EDGES + i];
    float nw = dinv[s] * EW[i] * dinv[t];
    int pos = atomicAdd(&cursor[t], 1);
    rec[pos] = make_int2(s, __float_as_int(nw));
}

// ---------------- aggregation: Y = S*X + dinv2 .* X  (bf16 out) ----------------

__global__ __launch_bounds__(256) void agg_kernel(const unsigned short* __restrict__ Xb,
                                                  const float* __restrict__ dinv2,
                                                  const int* __restrict__ offs,
                                                  const int2* __restrict__ rec,
                                                  unsigned short* __restrict__ Yb) {
    int node = blockIdx.x * 4 + (threadIdx.x >> 6);
    int lane = threadIdx.x & 63;
    if (node >= N_NODES) return;
    int e0 = offs[node], e1 = offs[node + 1];
    float a0, a1;
    {
        float s = dinv2[node];
        ushort2 xv = *(const ushort2*)(Xb + (size_t)node * 128 + lane * 2);
        a0 = s * bf2f(xv.x);
        a1 = s * bf2f(xv.y);
    }
    for (int e = e0; e < e1; ++e) {
        int2 r = rec[e];
        float w = __int_as_float(r.y);
        ushort2 xv = *(const ushort2*)(Xb + (size_t)r.x * 128 + lane * 2);
        a0 = fmaf(w, bf2f(xv.x), a0);
        a1 = fmaf(w, bf2f(xv.y), a1);
    }
    ushort2 o;
    o.x = f2bf(a0);
    o.y = f2bf(a1);
    *(ushort2*)(Yb + (size_t)node * 128 + lane * 2) = o;
}

// ---------------- GEMM1: Lin[:, g*128:] = Y @ W_g + b_g (bf16 out) ----------------

__global__ __launch_bounds__(256) void gemm1_kernel(const unsigned short* __restrict__ Yb,
                                                    const unsigned short* __restrict__ Wf,
                                                    const float* __restrict__ bz,
                                                    const float* __restrict__ br,
                                                    const float* __restrict__ bh,
                                                    unsigned short* __restrict__ Lin) {
    int g = blockIdx.y;
    int wave = threadIdx.x >> 6, lane = threadIdx.x & 63;
    int rowbase = blockIdx.x * 128 + wave * 32;
    const unsigned short* W = Wf + g * (128 * 128);
    const float* bias = (g == 0) ? bz : (g == 1) ? br : bh;
    f32x4_t acc[2][8];
    #pragma unroll
    for (int rt = 0; rt < 2; ++rt)
        #pragma unroll
        for (int nt = 0; nt < 8; ++nt) acc[rt][nt] = f32x4_t{0.f, 0.f, 0.f, 0.f};
    int r0 = rowbase + (lane & 15);
    int kg = 8 * (lane >> 4);
    #pragma unroll
    for (int ks = 0; ks < 4; ++ks) {
        bf16x8_t a0 = *(const bf16x8_t*)(Yb + (size_t)r0 * 128 + ks * 32 + kg);
        bf16x8_t a1 = *(const bf16x8_t*)(Yb + (size_t)(r0 + 16) * 128 + ks * 32 + kg);
        #pragma unroll
        for (int nt = 0; nt < 8; ++nt) {
            bf16x8_t b = *(const bf16x8_t*)(W + ((nt * 4 + ks) * 64 + lane) * 8);
            acc[0][nt] = __builtin_amdgcn_mfma_f32_16x16x32_bf16(a0, b, acc[0][nt], 0, 0, 0);
            acc[1][nt] = __builtin_amdgcn_mfma_f32_16x16x32_bf16(a1, b, acc[1][nt], 0, 0, 0);
        }
    }
    #pragma unroll
    for (int nt = 0; nt < 8; ++nt) {
        int col = nt * 16 + (lane & 15);
        float bv = bias[col];
        #pragma unroll
        for (int rt = 0; rt < 2; ++rt)
            #pragma unroll
            for (int r = 0; r < 4; ++r) {
                int row = rowbase + rt * 16 + 4 * (lane >> 4) + r;
                Lin[(size_t)row * 384 + g * 128 + col] = f2bf(acc[rt][nt][r] + bv);
            }
    }
}

// ---------------- fused gates: Z, R, H~, out ----------------

__global__ __launch_bounds__(256) void gates_kernel(const unsigned short* __restrict__ Lin,
                                                    const unsigned short* __restrict__ Hb,
                                                    const float* __restrict__ Hf,
                                                    const unsigned short* __restrict__ Wlf,
                                                    const float* __restrict__ blz,
                                                    const float* __restrict__ blr,
                                                    const float* __restrict__ blh,
                                                    float* __restrict__ out) {
    __shared__ unsigned short hrt[4][32][136];
    int wave = threadIdx.x >> 6, lane = threadIdx.x & 63;
    int rowbase = blockIdx.x * 128 + wave * 32;
    int rlo = lane & 15;
    int kg = 8 * (lane >> 4);
    const unsigned short* Wz = Wlf;
    const unsigned short* Wr = Wlf + 256 * 128;
    const unsigned short* Wh = Wlf + 2 * 256 * 128;

    float zv[2][8][4], hv[2][8][4];

    // ---- phase Z ----
    {
        f32x4_t acc[2][8];
        #pragma unroll
        for (int rt = 0; rt < 2; ++rt)
            #pragma unroll
            for (int nt = 0; nt < 8; ++nt) acc[rt][nt] = f32x4_t{0.f, 0.f, 0.f, 0.f};
        #pragma unroll
        for (int ks = 0; ks < 8; ++ks) {
            bf16x8_t a0, a1;
            if (ks < 4) {
                a0 = *(const bf16x8_t*)(Lin + (size_t)(rowbase + rlo) * 384 + ks * 32 + kg);
                a1 = *(const bf16x8_t*)(Lin + (size_t)(rowbase + 16 + rlo) * 384 + ks * 32 + kg);
            } else {
                a0 = *(const bf16x8_t*)(Hb + (size_t)(rowbase + rlo) * 128 + (ks - 4) * 32 + kg);
                a1 = *(const bf16x8_t*)(Hb + (size_t)(rowbase + 16 + rlo) * 128 + (ks - 4) * 32 + kg);
            }
            #pragma unroll
            for (int nt = 0; nt < 8; ++nt) {
                bf16x8_t b = *(const bf16x8_t*)(Wz + ((nt * 8 + ks) * 64 + lane) * 8);
                acc[0][nt] = __builtin_amdgcn_mfma_f32_16x16x32_bf16(a0, b, acc[0][nt], 0, 0, 0);
                acc[1][nt] = __builtin_amdgcn_mfma_f32_16x16x32_bf16(a1, b, acc[1][nt], 0, 0, 0);
            }
        }
        #pragma unroll
        for (int nt = 0; nt < 8; ++nt) {
            int col = nt * 16 + rlo;
            float bv = blz[col];
            #pragma unroll
            for (int rt = 0; rt < 2; ++rt)
                #pragma unroll
                for (int r = 0; r < 4; ++r) {
                    float p = acc[rt][nt][r] + bv;
                    zv[rt][nt][r] = 1.0f / (1.0f + __expf(-p));
                    int row = rowbase + rt * 16 + 4 * (lane >> 4) + r;
                    int rc = (row < N_NODES) ? row : (N_NODES - 1);
                    hv[rt][nt][r] = Hf[(size_t)rc * 128 + col];
                }
        }
    }

    // ---- phase R -> HR into LDS ----
    {
        f32x4_t acc[2][8];
        #pragma unroll
        for (int rt = 0; rt < 2; ++rt)
            #pragma unroll
            for (int nt = 0; nt < 8; ++nt) acc[rt][nt] = f32x4_t{0.f, 0.f, 0.f, 0.f};
        #pragma unroll
        for (int ks = 0; ks < 8; ++ks) {
            bf16x8_t a0, a1;
            if (ks < 4) {
                a0 = *(const bf16x8_t*)(Lin + (size_t)(rowbase + rlo) * 384 + 128 + ks * 32 + kg);
                a1 = *(const bf16x8_t*)(Lin + (size_t)(rowbase + 16 + rlo) * 384 + 128 + ks * 32 + kg);
            } else {
                a0 = *(const bf16x8_t*)(Hb + (size_t)(rowbase + rlo) * 128 + (ks - 4) * 32 + kg);
                a1 = *(const bf16x8_t*)(Hb + (size_t)(rowbase + 16 + rlo) * 128 + (ks - 4) * 32 + kg);
            }
            #pragma unroll
            for (int nt = 0; nt < 8; ++nt) {
                bf16x8_t b = *(const bf16x8_t*)(Wr + ((nt * 8 + ks) * 64 + lane) * 8);
                acc[0][nt] = __builtin_amdgcn_mfma_f32_16x16x32_bf16(a0, b, acc[0][nt], 0, 0, 0);
                acc[1][nt] = __builtin_amdgcn_mfma_f32_16x16x32_bf16(a1, b, acc[1][nt], 0, 0, 0);
            }
        }
        #pragma unroll
        for (int nt = 0; nt < 8; ++nt) {
            int col = nt * 16 + rlo;
            float bv = blr[col];
            #pragma unroll
            for (int rt = 0; rt < 2; ++rt)
                #pragma unroll
                for (int r = 0; r < 4; ++r) {
                    float p = acc[rt][nt][r] + bv;
                    float rv = 1.0f / (1.0f + __expf(-p));
                    hrt[wave][rt * 16 + 4 * (lane >> 4) + r][col] = f2bf(hv[rt][nt][r] * rv);
                }
        }
        __syncthreads();
    }

    // ---- phase H~ + combine ----
    {
        f32x4_t acc[2][8];
        #pragma unroll
        for (int rt = 0; rt < 2; ++rt)
            #pragma unroll
            for (int nt = 0; nt < 8; ++nt) acc[rt][nt] = f32x4_t{0.f, 0.f, 0.f, 0.f};
        #pragma unroll
        for (int ks = 0; ks < 8; ++ks) {
            bf16x8_t a0, a1;
            if (ks < 4) {
                a0 = *(const bf16x8_t*)(Lin + (size_t)(rowbase + rlo) * 384 + 256 + ks * 32 + kg);
                a1 = *(const bf16x8_t*)(Lin + (size_t)(rowbase + 16 + rlo) * 384 + 256 + ks * 32 + kg);
            } else {
                a0 = *(const bf16x8_t*)(&hrt[wave][rlo][(ks - 4) * 32 + kg]);
                a1 = *(const bf16x8_t*)(&hrt[wave][16 + rlo][(ks - 4) * 32 + kg]);
            }
            #pragma unroll
            for (int nt = 0; nt < 8; ++nt) {
                bf16x8_t b = *(const bf16x8_t*)(Wh + ((nt * 8 + ks) * 64 + lane) * 8);
                acc[0][nt] = __builtin_amdgcn_mfma_f32_16x16x32_bf16(a0, b, acc[0][nt], 0, 0, 0);
                acc[1][nt] = __builtin_amdgcn_mfma_f32_16x16x32_bf16(a1, b, acc[1][nt], 0, 0, 0);
            }
        }
        #pragma unroll
        for (int nt = 0; nt < 8; ++nt) {
            int col = nt * 16 + rlo;
            float bv = blh[col];
            #pragma unroll
            for (int rt = 0; rt < 2; ++rt)
                #pragma unroll
                for (int r = 0; r < 4; ++r) {
                    float p = acc[rt][nt][r] + bv;
                    float t = __expf(-2.0f * fabsf(p));
                    float th = (1.0f - t) / (1.0f + t);
                    th = copysignf(th, p);
                    float z = zv[rt][nt][r];
                    float o = z * hv[rt][nt][r] + (1.0f - z) * th;
                    int row = rowbase + rt * 16 + 4 * (lane >> 4) + r;
                    if (row < N_NODES) out[(size_t)row * 128 + col] = o;
                }
        }
    }
}

// ---------------- launch ----------------

extern "C" void kernel_launch(void* const* d_in, const int* in_sizes, int n_in,
                              void* d_out, int out_size, void* d_ws, size_t ws_size,
                              hipStream_t stream) {
    const float*      X   = (const float*)d_in[0];
    const int*        EI  = (const int*)d_in[1];    // harness delivers integer inputs as int32
    const float*      EW  = (const float*)d_in[2];
    const float*      Hf  = (const float*)d_in[3];
    const float*      Wz  = (const float*)d_in[4];
    const float*      bz  = (const float*)d_in[5];
    const float*      Wr  = (const float*)d_in[6];
    const float*      br  = (const float*)d_in[7];
    const float*      Wh  = (const float*)d_in[8];
    const float*      bh  = (const float*)d_in[9];
    const float*      Wlz = (const float*)d_in[10];
    const float*      blz = (const float*)d_in[11];
    const float*      Wlr = (const float*)d_in[12];
    const float*      blr = (const float*)d_in[13];
    const float*      Wlh = (const float*)d_in[14];
    const float*      blh = (const float*)d_in[15];
    float* out = (float*)d_out;

    char* p = (char*)d_ws;
    auto alloc = [&](size_t bytes) {
        char* r = p;
        p += (bytes + 255) & ~(size_t)255;
        return r;
    };
    float* deg    = (float*)alloc(M_PAD * 4);
    int*   counts = (int*)alloc(M_PAD * 4);
    int*   offs   = (int*)alloc((M_PAD + 1) * 4);
    int*   cursor = (int*)alloc(M_PAD * 4);
    float* dinv   = (float*)alloc(M_PAD * 4);
    float* dinv2  = (float*)alloc(M_PAD * 4);
    int2*  rec    = (int2*)alloc((size_t)N_EDGES * 8);
    unsigned short* Xb  = (unsigned short*)alloc((size_t)M_PAD * 128 * 2);
    unsigned short* Hb  = (unsigned short*)alloc((size_t)M_PAD * 128 * 2);
    unsigned short* Yb  = (unsigned short*)alloc((size_t)M_PAD * 128 * 2);
    unsigned short* Lin = (unsigned short*)alloc((size_t)M_PAD * 384 * 2);
    unsigned short* Wf  = (unsigned short*)alloc(3 * 128 * 128 * 2);
    unsigned short* Wlf = (unsigned short*)alloc(3 * 256 * 128 * 2);

    // zero deg + counts (adjacent, both 256B-aligned sizes)
    zero_kernel<<<(2 * M_PAD + 255) / 256, 256, 0, stream>>>((int*)deg, 2 * M_PAD);

    wfrag_kernel<<<72, 256, 0, stream>>>(Wz, Wr, Wh, Wlz, Wlr, Wlh, Wf, Wlf);
    convert_kernel<<<6250, 256, 0, stream>>>(X, Hf, Xb, Hb);
    pass1_kernel<<<3125, 256, 0, stream>>>(EI, EW, deg, counts);
    node_kernel<<<196, 256, 0, stream>>>(deg, dinv, dinv2);
    scan_kernel<<<1, 1024, 0, stream>>>(counts, offs, cursor);
    fill_kernel<<<3125, 256, 0, stream>>>(EI, EW, dinv, cursor, rec);
    agg_kernel<<<12500, 256, 0, stream>>>(Xb, dinv2, offs, rec, Yb);
    gemm1_kernel<<<dim3(NBLK, 3), 256, 0, stream>>>(Yb, Wf, bz, br, bh, Lin);
    gates_kernel<<<NBLK, 256, 0, stream>>>(Lin, Hb, Hf, Wlf, blz, blr, blh, out);
}

// Round 3
// 368.873 us; speedup vs baseline: 1.3089x; 1.3089x over previous
//
#include <hip/hip_runtime.h>
#include <hip/hip_bf16.h>

#define N_NODES 50000
#define N_EDGES 800000
#define M_PAD   50048   // 391 * 128
#define NBLK    391
#define SCAN_NBLK 49    // ceil(50000 / 1024)

typedef __attribute__((ext_vector_type(8))) short bf16x8_t;
typedef __attribute__((ext_vector_type(4))) float f32x4_t;

__device__ __forceinline__ unsigned short f2bf(float f) {
    unsigned u = __float_as_uint(f);
    u += 0x7FFFu + ((u >> 16) & 1u);
    return (unsigned short)(u >> 16);
}
__device__ __forceinline__ float bf2f(unsigned short h) {
    return __uint_as_float(((unsigned)h) << 16);
}

// ---------------- small prep kernels ----------------

__global__ void zero_kernel(int* p, int n) {
    int i = blockIdx.x * 256 + threadIdx.x;
    if (i < n) p[i] = 0;
}

__global__ void convert_kernel(const float* __restrict__ X, const float* __restrict__ Hsrc,
                               unsigned short* __restrict__ Xb, unsigned short* __restrict__ Hb) {
    int i = blockIdx.x * 256 + threadIdx.x;          // quad index
    if (i >= N_NODES * 32) return;
    float4 x = ((const float4*)X)[i];
    float4 h = ((const float4*)Hsrc)[i];
    ushort4 a, b;
    a.x = f2bf(x.x); a.y = f2bf(x.y); a.z = f2bf(x.z); a.w = f2bf(x.w);
    b.x = f2bf(h.x); b.y = f2bf(h.y); b.z = f2bf(h.z); b.w = f2bf(h.w);
    ((ushort4*)Xb)[i] = a;
    ((ushort4*)Hb)[i] = b;
}

// Pack weights into MFMA B-fragment order.
// For matrix W[K][N] row-major: frag element j of lane l at (nt, ks) is
// W[ks*32 + 8*(l>>4) + j][nt*16 + (l&15)], stored contiguously 8 per lane.
__global__ void wfrag_kernel(const float* __restrict__ Wz, const float* __restrict__ Wr,
                             const float* __restrict__ Wh,
                             const float* __restrict__ Wlz, const float* __restrict__ Wlr,
                             const float* __restrict__ Wlh,
                             unsigned short* __restrict__ Wf, unsigned short* __restrict__ Wlf) {
    int tid = blockIdx.x * 256 + threadIdx.x;
    if (tid < 3 * 2048) {            // W_* : K=128 (4 ksteps), N=128 (8 ntiles)
        int m = tid / 2048, t = tid % 2048;
        int nt = t / 256, ks = (t / 64) % 4, lane = t % 64;
        const float* W = (m == 0) ? Wz : (m == 1) ? Wr : Wh;
        unsigned short* dst = Wf + m * 128 * 128 + ((nt * 4 + ks) * 64 + lane) * 8;
        int n = nt * 16 + (lane & 15);
        int k0 = ks * 32 + 8 * (lane >> 4);
        #pragma unroll
        for (int j = 0; j < 8; ++j) dst[j] = f2bf(W[(k0 + j) * 128 + n]);
    } else {
        int u = tid - 3 * 2048;
        if (u < 3 * 4096) {          // Wl_* : K=256 (8 ksteps), N=128
            int m = u / 4096, t = u % 4096;
            int nt = t / 512, ks = (t / 64) % 8, lane = t % 64;
            const float* W = (m == 0) ? Wlz : (m == 1) ? Wlr : Wlh;
            unsigned short* dst = Wlf + m * 256 * 128 + ((nt * 8 + ks) * 64 + lane) * 8;
            int n = nt * 16 + (lane & 15);
            int k0 = ks * 32 + 8 * (lane >> 4);
            #pragma unroll
            for (int j = 0; j < 8; ++j) dst[j] = f2bf(W[(k0 + j) * 128 + n]);
        }
    }
}

// ---------------- graph prep ----------------

__global__ void pass1_kernel(const int* __restrict__ EI, const float* __restrict__ EW,
                             float* __restrict__ deg, int* __restrict__ counts) {
    int i = blockIdx.x * 256 + threadIdx.x;
    if (i >= N_EDGES) return;
    int t = EI[N_EDGES + i];
    atomicAdd(&deg[t], EW[i]);
    atomicAdd(&counts[t], 1);
}

__global__ void node_kernel(const float* __restrict__ deg, float* __restrict__ dinv,
                            float* __restrict__ dinv2) {
    int i = blockIdx.x * 256 + threadIdx.x;
    if (i >= N_NODES) return;
    float d = deg[i] + 1.0f;
    float di = rsqrtf(d);
    dinv[i] = di;
    dinv2[i] = di * di;
}

// ---- hierarchical exclusive scan over counts (3 tiny kernels) ----

__global__ void scan1_kernel(const int* __restrict__ counts, int* __restrict__ partials) {
    __shared__ int red[256];
    int t = threadIdx.x;
    int base = (blockIdx.x * 256 + t) * 4;
    int s = 0;
    #pragma unroll
    for (int i = 0; i < 4; ++i) {
        int idx = base + i;
        if (idx < N_NODES) s += counts[idx];
    }
    red[t] = s;
    __syncthreads();
    #pragma unroll
    for (int off = 128; off > 0; off >>= 1) {
        if (t < off) red[t] += red[t + off];
        __syncthreads();
    }
    if (t == 0) partials[blockIdx.x] = red[0];
}

__global__ void scan2_kernel(const int* __restrict__ partials, int* __restrict__ blockoff,
                             int* __restrict__ offs) {
    int t = threadIdx.x;   // single wave of 64
    int orig = (t < SCAN_NBLK) ? partials[t] : 0;
    int v = orig;
    #pragma unroll
    for (int d = 1; d < 64; d <<= 1) {
        int u = __shfl_up(v, d, 64);
        if (t >= d) v += u;
    }
    if (t < SCAN_NBLK) blockoff[t] = v - orig;          // exclusive block offset
    if (t == SCAN_NBLK - 1) offs[N_NODES] = v;          // total edge count
}

__global__ void scan3_kernel(const int* __restrict__ counts, const int* __restrict__ blockoff,
                             int* __restrict__ offs, int* __restrict__ cursor) {
    __shared__ int sc[256];
    int t = threadIdx.x;
    int base = (blockIdx.x * 256 + t) * 4;
    int c[4];
    int s = 0;
    #pragma unroll
    for (int i = 0; i < 4; ++i) {
        int idx = base + i;
        c[i] = (idx < N_NODES) ? counts[idx] : 0;
        s += c[i];
    }
    sc[t] = s;
    __syncthreads();
    #pragma unroll
    for (int off = 1; off < 256; off <<= 1) {
        int v = (t >= off) ? sc[t - off] : 0;
        __syncthreads();
        sc[t] += v;
        __syncthreads();
    }
    int run = blockoff[blockIdx.x] + sc[t] - s;          // exclusive prefix
    #pragma unroll
    for (int i = 0; i < 4; ++i) {
        int idx = base + i;
        if (idx < N_NODES) { offs[idx] = run; cursor[idx] = run; run += c[i]; }
    }
}

__global__ void fill_kernel(const int* __restrict__ EI, const float* __restrict__ EW,
                            const float* __restrict__ dinv, int* __restrict__ cursor,
                            int2* __restrict__ rec) {
    int i = blockIdx.x * 256 + threadIdx.x;
    if (i >= N_EDGES) return;
    int s = EI[i];
    int t = EI[N_EDGES + i];
    float nw = dinv[s] * EW[i] * dinv[t];
    int pos = atomicAdd(&cursor[t], 1);
    rec[pos] = make_int2(s, __float_as_int(nw));
}

// ---------------- aggregation: Y = S*X + dinv2 .* X  (bf16 out) ----------------

__global__ __launch_bounds__(256) void agg_kernel(const unsigned short* __restrict__ Xb,
                                                  const float* __restrict__ dinv2,
                                                  const int* __restrict__ offs,
                                                  const int2* __restrict__ rec,
                                                  unsigned short* __restrict__ Yb) {
    int node = blockIdx.x * 4 + (threadIdx.x >> 6);
    int lane = threadIdx.x & 63;
    if (node >= N_NODES) return;
    int e0 = offs[node], e1 = offs[node + 1];
    float a0, a1;
    {
        float s = dinv2[node];
        ushort2 xv = *(const ushort2*)(Xb + (size_t)node * 128 + lane * 2);
        a0 = s * bf2f(xv.x);
        a1 = s * bf2f(xv.y);
    }
    for (int e = e0; e < e1; ++e) {
        int2 r = rec[e];
        float w = __int_as_float(r.y);
        ushort2 xv = *(const ushort2*)(Xb + (size_t)r.x * 128 + lane * 2);
        a0 = fmaf(w, bf2f(xv.x), a0);
        a1 = fmaf(w, bf2f(xv.y), a1);
    }
    ushort2 o;
    o.x = f2bf(a0);
    o.y = f2bf(a1);
    *(ushort2*)(Yb + (size_t)node * 128 + lane * 2) = o;
}

// ---------------- GEMM1: Lin[:, g*128:] = Y @ W_g + b_g (bf16 out) ----------------

__global__ __launch_bounds__(256) void gemm1_kernel(const unsigned short* __restrict__ Yb,
                                                    const unsigned short* __restrict__ Wf,
                                                    const float* __restrict__ bz,
                                                    const float* __restrict__ br,
                                                    const float* __restrict__ bh,
                                                    unsigned short* __restrict__ Lin) {
    int g = blockIdx.y;
    int wave = threadIdx.x >> 6, lane = threadIdx.x & 63;
    int rowbase = blockIdx.x * 128 + wave * 32;
    const unsigned short* W = Wf + g * (128 * 128);
    const float* bias = (g == 0) ? bz : (g == 1) ? br : bh;
    f32x4_t acc[2][8];
    #pragma unroll
    for (int rt = 0; rt < 2; ++rt)
        #pragma unroll
        for (int nt = 0; nt < 8; ++nt) acc[rt][nt] = f32x4_t{0.f, 0.f, 0.f, 0.f};
    int r0 = rowbase + (lane & 15);
    int kg = 8 * (lane >> 4);
    #pragma unroll
    for (int ks = 0; ks < 4; ++ks) {
        bf16x8_t a0 = *(const bf16x8_t*)(Yb + (size_t)r0 * 128 + ks * 32 + kg);
        bf16x8_t a1 = *(const bf16x8_t*)(Yb + (size_t)(r0 + 16) * 128 + ks * 32 + kg);
        #pragma unroll
        for (int nt = 0; nt < 8; ++nt) {
            bf16x8_t b = *(const bf16x8_t*)(W + ((nt * 4 + ks) * 64 + lane) * 8);
            acc[0][nt] = __builtin_amdgcn_mfma_f32_16x16x32_bf16(a0, b, acc[0][nt], 0, 0, 0);
            acc[1][nt] = __builtin_amdgcn_mfma_f32_16x16x32_bf16(a1, b, acc[1][nt], 0, 0, 0);
        }
    }
    #pragma unroll
    for (int nt = 0; nt < 8; ++nt) {
        int col = nt * 16 + (lane & 15);
        float bv = bias[col];
        #pragma unroll
        for (int rt = 0; rt < 2; ++rt)
            #pragma unroll
            for (int r = 0; r < 4; ++r) {
                int row = rowbase + rt * 16 + 4 * (lane >> 4) + r;
                Lin[(size_t)row * 384 + g * 128 + col] = f2bf(acc[rt][nt][r] + bv);
            }
    }
}

// ---------------- fused gates: Z, R, H~, out ----------------

__global__ __launch_bounds__(256) void gates_kernel(const unsigned short* __restrict__ Lin,
                                                    const unsigned short* __restrict__ Hb,
                                                    const float* __restrict__ Hf,
                                                    const unsigned short* __restrict__ Wlf,
                                                    const float* __restrict__ blz,
                                                    const float* __restrict__ blr,
                                                    const float* __restrict__ blh,
                                                    float* __restrict__ out) {
    __shared__ unsigned short hrt[4][32][136];
    int wave = threadIdx.x >> 6, lane = threadIdx.x & 63;
    int rowbase = blockIdx.x * 128 + wave * 32;
    int rlo = lane & 15;
    int kg = 8 * (lane >> 4);
    const unsigned short* Wz = Wlf;
    const unsigned short* Wr = Wlf + 256 * 128;
    const unsigned short* Wh = Wlf + 2 * 256 * 128;

    float zv[2][8][4], hv[2][8][4];

    // ---- phase Z ----
    {
        f32x4_t acc[2][8];
        #pragma unroll
        for (int rt = 0; rt < 2; ++rt)
            #pragma unroll
            for (int nt = 0; nt < 8; ++nt) acc[rt][nt] = f32x4_t{0.f, 0.f, 0.f, 0.f};
        #pragma unroll
        for (int ks = 0; ks < 8; ++ks) {
            bf16x8_t a0, a1;
            if (ks < 4) {
                a0 = *(const bf16x8_t*)(Lin + (size_t)(rowbase + rlo) * 384 + ks * 32 + kg);
                a1 = *(const bf16x8_t*)(Lin + (size_t)(rowbase + 16 + rlo) * 384 + ks * 32 + kg);
            } else {
                a0 = *(const bf16x8_t*)(Hb + (size_t)(rowbase + rlo) * 128 + (ks - 4) * 32 + kg);
                a1 = *(const bf16x8_t*)(Hb + (size_t)(rowbase + 16 + rlo) * 128 + (ks - 4) * 32 + kg);
            }
            #pragma unroll
            for (int nt = 0; nt < 8; ++nt) {
                bf16x8_t b = *(const bf16x8_t*)(Wz + ((nt * 8 + ks) * 64 + lane) * 8);
                acc[0][nt] = __builtin_amdgcn_mfma_f32_16x16x32_bf16(a0, b, acc[0][nt], 0, 0, 0);
                acc[1][nt] = __builtin_amdgcn_mfma_f32_16x16x32_bf16(a1, b, acc[1][nt], 0, 0, 0);
            }
        }
        #pragma unroll
        for (int nt = 0; nt < 8; ++nt) {
            int col = nt * 16 + rlo;
            float bv = blz[col];
            #pragma unroll
            for (int rt = 0; rt < 2; ++rt)
                #pragma unroll
                for (int r = 0; r < 4; ++r) {
                    float p = acc[rt][nt][r] + bv;
                    zv[rt][nt][r] = 1.0f / (1.0f + __expf(-p));
                    int row = rowbase + rt * 16 + 4 * (lane >> 4) + r;
                    int rc = (row < N_NODES) ? row : (N_NODES - 1);
                    hv[rt][nt][r] = Hf[(size_t)rc * 128 + col];
                }
        }
    }

    // ---- phase R -> HR into LDS ----
    {
        f32x4_t acc[2][8];
        #pragma unroll
        for (int rt = 0; rt < 2; ++rt)
            #pragma unroll
            for (int nt = 0; nt < 8; ++nt) acc[rt][nt] = f32x4_t{0.f, 0.f, 0.f, 0.f};
        #pragma unroll
        for (int ks = 0; ks < 8; ++ks) {
            bf16x8_t a0, a1;
            if (ks < 4) {
                a0 = *(const bf16x8_t*)(Lin + (size_t)(rowbase + rlo) * 384 + 128 + ks * 32 + kg);
                a1 = *(const bf16x8_t*)(Lin + (size_t)(rowbase + 16 + rlo) * 384 + 128 + ks * 32 + kg);
            } else {
                a0 = *(const bf16x8_t*)(Hb + (size_t)(rowbase + rlo) * 128 + (ks - 4) * 32 + kg);
                a1 = *(const bf16x8_t*)(Hb + (size_t)(rowbase + 16 + rlo) * 128 + (ks - 4) * 32 + kg);
            }
            #pragma unroll
            for (int nt = 0; nt < 8; ++nt) {
                bf16x8_t b = *(const bf16x8_t*)(Wr + ((nt * 8 + ks) * 64 + lane) * 8);
                acc[0][nt] = __builtin_amdgcn_mfma_f32_16x16x32_bf16(a0, b, acc[0][nt], 0, 0, 0);
                acc[1][nt] = __builtin_amdgcn_mfma_f32_16x16x32_bf16(a1, b, acc[1][nt], 0, 0, 0);
            }
        }
        #pragma unroll
        for (int nt = 0; nt < 8; ++nt) {
            int col = nt * 16 + rlo;
            float bv = blr[col];
            #pragma unroll
            for (int rt = 0; rt < 2; ++rt)
                #pragma unroll
                for (int r = 0; r < 4; ++r) {
                    float p = acc[rt][nt][r] + bv;
                    float rv = 1.0f / (1.0f + __expf(-p));
                    hrt[wave][rt * 16 + 4 * (lane >> 4) + r][col] = f2bf(hv[rt][nt][r] * rv);
                }
        }
        __syncthreads();
    }

    // ---- phase H~ + combine ----
    {
        f32x4_t acc[2][8];
        #pragma unroll
        for (int rt = 0; rt < 2; ++rt)
            #pragma unroll
            for (int nt = 0; nt < 8; ++nt) acc[rt][nt] = f32x4_t{0.f, 0.f, 0.f, 0.f};
        #pragma unroll
        for (int ks = 0; ks < 8; ++ks) {
            bf16x8_t a0, a1;
            if (ks < 4) {
                a0 = *(const bf16x8_t*)(Lin + (size_t)(rowbase + rlo) * 384 + 256 + ks * 32 + kg);
                a1 = *(const bf16x8_t*)(Lin + (size_t)(rowbase + 16 + rlo) * 384 + 256 + ks * 32 + kg);
            } else {
                a0 = *(const bf16x8_t*)(&hrt[wave][rlo][(ks - 4) * 32 + kg]);
                a1 = *(const bf16x8_t*)(&hrt[wave][16 + rlo][(ks - 4) * 32 + kg]);
            }
            #pragma unroll
            for (int nt = 0; nt < 8; ++nt) {
                bf16x8_t b = *(const bf16x8_t*)(Wh + ((nt * 8 + ks) * 64 + lane) * 8);
                acc[0][nt] = __builtin_amdgcn_mfma_f32_16x16x32_bf16(a0, b, acc[0][nt], 0, 0, 0);
                acc[1][nt] = __builtin_amdgcn_mfma_f32_16x16x32_bf16(a1, b, acc[1][nt], 0, 0, 0);
            }
        }
        #pragma unroll
        for (int nt = 0; nt < 8; ++nt) {
            int col = nt * 16 + rlo;
            float bv = blh[col];
            #pragma unroll
            for (int rt = 0; rt < 2; ++rt)
                #pragma unroll
                for (int r = 0; r < 4; ++r) {
                    float p = acc[rt][nt][r] + bv;
                    float t = __expf(-2.0f * fabsf(p));
                    float th = (1.0f - t) / (1.0f + t);
                    th = copysignf(th, p);
                    float z = zv[rt][nt][r];
                    float o = z * hv[rt][nt][r] + (1.0f - z) * th;
                    int row = rowbase + rt * 16 + 4 * (lane >> 4) + r;
                    if (row < N_NODES) out[(size_t)row * 128 + col] = o;
                }
        }
    }
}

// ---------------- launch ----------------

extern "C" void kernel_launch(void* const* d_in, const int* in_sizes, int n_in,
                              void* d_out, int out_size, void* d_ws, size_t ws_size,
                              hipStream_t stream) {
    const float*      X   = (const float*)d_in[0];
    const int*        EI  = (const int*)d_in[1];    // harness delivers integer inputs as int32
    const float*      EW  = (const float*)d_in[2];
    const float*      Hf  = (const float*)d_in[3];
    const float*      Wz  = (const float*)d_in[4];
    const float*      bz  = (const float*)d_in[5];
    const float*      Wr  = (const float*)d_in[6];
    const float*      br  = (const float*)d_in[7];
    const float*      Wh  = (const float*)d_in[8];
    const float*      bh  = (const float*)d_in[9];
    const float*      Wlz = (const float*)d_in[10];
    const float*      blz = (const float*)d_in[11];
    const float*      Wlr = (const float*)d_in[12];
    const float*      blr = (const float*)d_in[13];
    const float*      Wlh = (const float*)d_in[14];
    const float*      blh = (const float*)d_in[15];
    float* out = (float*)d_out;

    char* p = (char*)d_ws;
    auto alloc = [&](size_t bytes) {
        char* r = p;
        p += (bytes + 255) & ~(size_t)255;
        return r;
    };
    float* deg    = (float*)alloc(M_PAD * 4);
    int*   counts = (int*)alloc(M_PAD * 4);
    int*   offs   = (int*)alloc((M_PAD + 1) * 4);
    int*   cursor = (int*)alloc(M_PAD * 4);
    float* dinv   = (float*)alloc(M_PAD * 4);
    float* dinv2  = (float*)alloc(M_PAD * 4);
    int*   partials = (int*)alloc(64 * 4);
    int*   blockoff = (int*)alloc(64 * 4);
    int2*  rec    = (int2*)alloc((size_t)N_EDGES * 8);
    unsigned short* Xb  = (unsigned short*)alloc((size_t)M_PAD * 128 * 2);
    unsigned short* Hb  = (unsigned short*)alloc((size_t)M_PAD * 128 * 2);
    unsigned short* Yb  = (unsigned short*)alloc((size_t)M_PAD * 128 * 2);
    unsigned short* Lin = (unsigned short*)alloc((size_t)M_PAD * 384 * 2);
    unsigned short* Wf  = (unsigned short*)alloc(3 * 128 * 128 * 2);
    unsigned short* Wlf = (unsigned short*)alloc(3 * 256 * 128 * 2);

    // zero deg + counts (adjacent, both 256B-aligned sizes)
    zero_kernel<<<(2 * M_PAD + 255) / 256, 256, 0, stream>>>((int*)deg, 2 * M_PAD);

    wfrag_kernel<<<72, 256, 0, stream>>>(Wz, Wr, Wh, Wlz, Wlr, Wlh, Wf, Wlf);
    convert_kernel<<<6250, 256, 0, stream>>>(X, Hf, Xb, Hb);
    pass1_kernel<<<3125, 256, 0, stream>>>(EI, EW, deg, counts);
    node_kernel<<<196, 256, 0, stream>>>(deg, dinv, dinv2);
    scan1_kernel<<<SCAN_NBLK, 256, 0, stream>>>(counts, partials);
    scan2_kernel<<<1, 64, 0, stream>>>(partials, blockoff, offs);
    scan3_kernel<<<SCAN_NBLK, 256, 0, stream>>>(counts, blockoff, offs, cursor);
    fill_kernel<<<3125, 256, 0, stream>>>(EI, EW, dinv, cursor, rec);
    agg_kernel<<<12500, 256, 0, stream>>>(Xb, dinv2, offs, rec, Yb);
    gemm1_kernel<<<dim3(NBLK, 3), 256, 0, stream>>>(Yb, Wf, bz, br, bh, Lin);
    gates_kernel<<<NBLK, 256, 0, stream>>>(Lin, Hb, Hf, Wlf, blz, blr, blh, out);
}

// Round 4
// 284.685 us; speedup vs baseline: 1.6959x; 1.2957x over previous
//
#include <hip/hip_runtime.h>
#include <hip/hip_bf16.h>

#define N_NODES 50000
#define N_EDGES 800000
#define M_PAD   50048   // 391 * 128
#define SCAN_NBLK 49    // ceil(50000 / 1024)
#define NBLK2   782     // M_PAD / 64

typedef __attribute__((ext_vector_type(8))) short bf16x8_t;
typedef __attribute__((ext_vector_type(4))) float f32x4_t;

__device__ __forceinline__ unsigned short f2bf(float f) {
    unsigned u = __float_as_uint(f);
    u += 0x7FFFu + ((u >> 16) & 1u);
    return (unsigned short)(u >> 16);
}
__device__ __forceinline__ float bf2f(unsigned short h) {
    return __uint_as_float(((unsigned)h) << 16);
}

// ---------------- small prep kernels ----------------

__global__ void zero_kernel(int* p, int n) {
    int i = blockIdx.x * 256 + threadIdx.x;
    if (i < n) p[i] = 0;
}

__global__ void convert_kernel(const float* __restrict__ X, const float* __restrict__ Hsrc,
                               unsigned short* __restrict__ Xb, unsigned short* __restrict__ Hb) {
    int i = blockIdx.x * 256 + threadIdx.x;          // quad index
    if (i >= N_NODES * 32) return;
    float4 x = ((const float4*)X)[i];
    float4 h = ((const float4*)Hsrc)[i];
    ushort4 a, b;
    a.x = f2bf(x.x); a.y = f2bf(x.y); a.z = f2bf(x.z); a.w = f2bf(x.w);
    b.x = f2bf(h.x); b.y = f2bf(h.y); b.z = f2bf(h.z); b.w = f2bf(h.w);
    ((ushort4*)Xb)[i] = a;
    ((ushort4*)Hb)[i] = b;
}

// Fuse: P_g = W_g @ Wl_g[:128,:]  (f32), c_g = b_g @ Wl_g[:128,:] + bl_g
__global__ void fuse_kernel(const float* __restrict__ Wz, const float* __restrict__ Wr,
                            const float* __restrict__ Wh,
                            const float* __restrict__ bz, const float* __restrict__ br,
                            const float* __restrict__ bh,
                            const float* __restrict__ Wlz, const float* __restrict__ Wlr,
                            const float* __restrict__ Wlh,
                            const float* __restrict__ blz, const float* __restrict__ blr,
                            const float* __restrict__ blh,
                            float* __restrict__ Pf, float* __restrict__ cg) {
    int tid = blockIdx.x * 256 + threadIdx.x;
    if (tid < 3 * 16384) {
        int g = tid / 16384, k = (tid / 128) % 128, n = tid & 127;
        const float* W  = (g == 0) ? Wz  : (g == 1) ? Wr  : Wh;
        const float* Wl = (g == 0) ? Wlz : (g == 1) ? Wlr : Wlh;
        float acc = 0.f;
        #pragma unroll 8
        for (int j = 0; j < 128; ++j)
            acc = fmaf(W[k * 128 + j], Wl[j * 128 + n], acc);
        Pf[tid] = acc;
    } else if (tid < 3 * 16384 + 384) {
        int u = tid - 3 * 16384;
        int g = u / 128, n = u & 127;
        const float* b  = (g == 0) ? bz  : (g == 1) ? br  : bh;
        const float* Wl = (g == 0) ? Wlz : (g == 1) ? Wlr : Wlh;
        const float* bl = (g == 0) ? blz : (g == 1) ? blr : blh;
        float acc = bl[n];
        #pragma unroll 8
        for (int j = 0; j < 128; ++j)
            acc = fmaf(b[j], Wl[j * 128 + n], acc);
        cg[u] = acc;
    }
}

// Pack 6 K=128 matrices into MFMA B-fragment order (bf16).
// m=0..2: fused P_g (f32, from Pf); m=3..5: Wl_g[128:,:] (f32, from inputs).
// Frag element j of lane l at (nt,ks): src[ks*32+8*(l>>4)+j][nt*16+(l&15)]
__global__ void wfrag2_kernel(const float* __restrict__ Pf,
                              const float* __restrict__ Wlz, const float* __restrict__ Wlr,
                              const float* __restrict__ Wlh,
                              unsigned short* __restrict__ Wf2) {
    int tid = blockIdx.x * 256 + threadIdx.x;
    if (tid >= 6 * 2048) return;
    int m = tid / 2048, t = tid % 2048;
    int nt = t / 256, ks = (t / 64) % 4, lane = t % 64;
    const float* src;
    if (m < 3) src = Pf + m * 16384;
    else       src = ((m == 3) ? Wlz : (m == 4) ? Wlr : Wlh) + 128 * 128;
    unsigned short* dst = Wf2 + m * 16384 + ((nt * 4 + ks) * 64 + lane) * 8;
    int n = nt * 16 + (lane & 15);
    int k0 = ks * 32 + 8 * (lane >> 4);
    #pragma unroll
    for (int j = 0; j < 8; ++j) dst[j] = f2bf(src[(k0 + j) * 128 + n]);
}

// ---------------- graph prep ----------------

__global__ void pass1_kernel(const int* __restrict__ EI, const float* __restrict__ EW,
                             float* __restrict__ deg, int* __restrict__ counts) {
    int i = blockIdx.x * 256 + threadIdx.x;
    if (i >= N_EDGES) return;
    int t = EI[N_EDGES + i];
    atomicAdd(&deg[t], EW[i]);
    atomicAdd(&counts[t], 1);
}

__global__ void node_kernel(const float* __restrict__ deg, float* __restrict__ dinv,
                            float* __restrict__ dinv2) {
    int i = blockIdx.x * 256 + threadIdx.x;
    if (i >= N_NODES) return;
    float d = deg[i] + 1.0f;
    float di = rsqrtf(d);
    dinv[i] = di;
    dinv2[i] = di * di;
}

// ---- hierarchical exclusive scan over counts ----

__global__ void scan1_kernel(const int* __restrict__ counts, int* __restrict__ partials) {
    __shared__ int red[256];
    int t = threadIdx.x;
    int base = (blockIdx.x * 256 + t) * 4;
    int s = 0;
    #pragma unroll
    for (int i = 0; i < 4; ++i) {
        int idx = base + i;
        if (idx < N_NODES) s += counts[idx];
    }
    red[t] = s;
    __syncthreads();
    #pragma unroll
    for (int off = 128; off > 0; off >>= 1) {
        if (t < off) red[t] += red[t + off];
        __syncthreads();
    }
    if (t == 0) partials[blockIdx.x] = red[0];
}

__global__ void scan2_kernel(const int* __restrict__ partials, int* __restrict__ blockoff,
                             int* __restrict__ offs) {
    int t = threadIdx.x;   // single wave of 64
    int orig = (t < SCAN_NBLK) ? partials[t] : 0;
    int v = orig;
    #pragma unroll
    for (int d = 1; d < 64; d <<= 1) {
        int u = __shfl_up(v, d, 64);
        if (t >= d) v += u;
    }
    if (t < SCAN_NBLK) blockoff[t] = v - orig;          // exclusive block offset
    if (t == SCAN_NBLK - 1) offs[N_NODES] = v;          // total edge count
}

__global__ void scan3_kernel(const int* __restrict__ counts, const int* __restrict__ blockoff,
                             int* __restrict__ offs, int* __restrict__ cursor) {
    __shared__ int sc[256];
    int t = threadIdx.x;
    int base = (blockIdx.x * 256 + t) * 4;
    int c[4];
    int s = 0;
    #pragma unroll
    for (int i = 0; i < 4; ++i) {
        int idx = base + i;
        c[i] = (idx < N_NODES) ? counts[idx] : 0;
        s += c[i];
    }
    sc[t] = s;
    __syncthreads();
    #pragma unroll
    for (int off = 1; off < 256; off <<= 1) {
        int v = (t >= off) ? sc[t - off] : 0;
        __syncthreads();
        sc[t] += v;
        __syncthreads();
    }
    int run = blockoff[blockIdx.x] + sc[t] - s;          // exclusive prefix
    #pragma unroll
    for (int i = 0; i < 4; ++i) {
        int idx = base + i;
        if (idx < N_NODES) { offs[idx] = run; cursor[idx] = run; run += c[i]; }
    }
}

__global__ void fill_kernel(const int* __restrict__ EI, const float* __restrict__ EW,
                            const float* __restrict__ dinv, int* __restrict__ cursor,
                            int2* __restrict__ rec) {
    int i = blockIdx.x * 256 + threadIdx.x;
    if (i >= N_EDGES) return;
    int s = EI[i];
    int t = EI[N_EDGES + i];
    float nw = dinv[s] * EW[i] * dinv[t];
    int pos = atomicAdd(&cursor[t], 1);
    rec[pos] = make_int2(s, __float_as_int(nw));
}

// ---------------- aggregation: Y = S*X + dinv2 .* X  (bf16 out) ----------------

__global__ __launch_bounds__(256) void agg_kernel(const unsigned short* __restrict__ Xb,
                                                  const float* __restrict__ dinv2,
                                                  const int* __restrict__ offs,
                                                  const int2* __restrict__ rec,
                                                  unsigned short* __restrict__ Yb) {
    int node = blockIdx.x * 4 + (threadIdx.x >> 6);
    int lane = threadIdx.x & 63;
    if (node >= N_NODES) return;
    int e0 = offs[node], e1 = offs[node + 1];
    float a0, a1;
    {
        float s = dinv2[node];
        ushort2 xv = *(const ushort2*)(Xb + (size_t)node * 128 + lane * 2);
        a0 = s * bf2f(xv.x);
        a1 = s * bf2f(xv.y);
    }
    for (int e = e0; e < e1; ++e) {
        int2 r = rec[e];
        float w = __int_as_float(r.y);
        ushort2 xv = *(const ushort2*)(Xb + (size_t)r.x * 128 + lane * 2);
        a0 = fmaf(w, bf2f(xv.x), a0);
        a1 = fmaf(w, bf2f(xv.y), a1);
    }
    ushort2 o;
    o.x = f2bf(a0);
    o.y = f2bf(a1);
    *(ushort2*)(Yb + (size_t)node * 128 + lane * 2) = o;
}

// ---------------- fused gates (weight-fused, 64 rows/block) ----------------
// Z  = sigmoid(Y@Az + H@Bz + cz)
// R  = sigmoid(Y@Ar + H@Br + cr)
// Ht = tanh   (Y@Ah + (H.R)@Bh + ch)
// out = Z.H + (1-Z).Ht

__global__ __launch_bounds__(256) void gates2_kernel(const unsigned short* __restrict__ Yb,
                                                     const unsigned short* __restrict__ Hb,
                                                     const float* __restrict__ Hf,
                                                     const unsigned short* __restrict__ Wf2,
                                                     const float* __restrict__ cg,
                                                     float* __restrict__ out) {
    __shared__ unsigned short rls[4][16][136];
    int wave = threadIdx.x >> 6, lane = threadIdx.x & 63;
    int rowbase = blockIdx.x * 64 + wave * 16;
    int rlo = lane & 15;
    int kg = 8 * (lane >> 4);
    int r0 = rowbase + rlo;

    const unsigned short* Az = Wf2;
    const unsigned short* Ar = Wf2 + 16384;
    const unsigned short* Ah = Wf2 + 2 * 16384;
    const unsigned short* Bz = Wf2 + 3 * 16384;
    const unsigned short* Br = Wf2 + 4 * 16384;
    const unsigned short* Bh = Wf2 + 5 * 16384;
    const float* cz = cg;
    const float* cr = cg + 128;
    const float* ch = cg + 256;

    // A-fragments for Y and H (live through both phases)
    bf16x8_t ay[4], ah[4];
    #pragma unroll
    for (int ks = 0; ks < 4; ++ks) {
        ay[ks] = *(const bf16x8_t*)(Yb + (size_t)r0 * 128 + ks * 32 + kg);
        ah[ks] = *(const bf16x8_t*)(Hb + (size_t)r0 * 128 + ks * 32 + kg);
    }

    // ---- phase R ----
    {
        f32x4_t acc[8];
        #pragma unroll
        for (int nt = 0; nt < 8; ++nt) acc[nt] = f32x4_t{0.f, 0.f, 0.f, 0.f};
        #pragma unroll
        for (int ks = 0; ks < 4; ++ks) {
            #pragma unroll
            for (int nt = 0; nt < 8; ++nt) {
                bf16x8_t b = *(const bf16x8_t*)(Ar + ((nt * 4 + ks) * 64 + lane) * 8);
                acc[nt] = __builtin_amdgcn_mfma_f32_16x16x32_bf16(ay[ks], b, acc[nt], 0, 0, 0);
            }
        }
        #pragma unroll
        for (int ks = 0; ks < 4; ++ks) {
            #pragma unroll
            for (int nt = 0; nt < 8; ++nt) {
                bf16x8_t b = *(const bf16x8_t*)(Br + ((nt * 4 + ks) * 64 + lane) * 8);
                acc[nt] = __builtin_amdgcn_mfma_f32_16x16x32_bf16(ah[ks], b, acc[nt], 0, 0, 0);
            }
        }
        #pragma unroll
        for (int nt = 0; nt < 8; ++nt) {
            int col = nt * 16 + rlo;
            float crv = cr[col];
            #pragma unroll
            for (int r = 0; r < 4; ++r) {
                float p = acc[nt][r] + crv;
                float rv = 1.0f / (1.0f + __expf(-p));
                rls[wave][4 * (lane >> 4) + r][col] = f2bf(rv);
            }
        }
        __syncthreads();
    }

    // ---- phase Z + H~ ----
    {
        f32x4_t az[8], ath[8];
        #pragma unroll
        for (int nt = 0; nt < 8; ++nt) {
            az[nt] = f32x4_t{0.f, 0.f, 0.f, 0.f};
            ath[nt] = f32x4_t{0.f, 0.f, 0.f, 0.f};
        }
        #pragma unroll
        for (int ks = 0; ks < 4; ++ks) {
            #pragma unroll
            for (int nt = 0; nt < 8; ++nt) {
                bf16x8_t bz_ = *(const bf16x8_t*)(Az + ((nt * 4 + ks) * 64 + lane) * 8);
                bf16x8_t bh_ = *(const bf16x8_t*)(Ah + ((nt * 4 + ks) * 64 + lane) * 8);
                az[nt]  = __builtin_amdgcn_mfma_f32_16x16x32_bf16(ay[ks], bz_, az[nt], 0, 0, 0);
                ath[nt] = __builtin_amdgcn_mfma_f32_16x16x32_bf16(ay[ks], bh_, ath[nt], 0, 0, 0);
            }
        }
        #pragma unroll
        for (int ks = 0; ks < 4; ++ks) {
            bf16x8_t rf = *(const bf16x8_t*)(&rls[wave][rlo][ks * 32 + kg]);
            bf16x8_t hr;
            #pragma unroll
            for (int j = 0; j < 8; ++j)
                hr[j] = (short)f2bf(bf2f((unsigned short)ah[ks][j]) * bf2f((unsigned short)rf[j]));
            #pragma unroll
            for (int nt = 0; nt < 8; ++nt) {
                bf16x8_t bz_ = *(const bf16x8_t*)(Bz + ((nt * 4 + ks) * 64 + lane) * 8);
                bf16x8_t bh_ = *(const bf16x8_t*)(Bh + ((nt * 4 + ks) * 64 + lane) * 8);
                az[nt]  = __builtin_amdgcn_mfma_f32_16x16x32_bf16(ah[ks], bz_, az[nt], 0, 0, 0);
                ath[nt] = __builtin_amdgcn_mfma_f32_16x16x32_bf16(hr, bh_, ath[nt], 0, 0, 0);
            }
        }
        #pragma unroll
        for (int nt = 0; nt < 8; ++nt) {
            int col = nt * 16 + rlo;
            float czv = cz[col];
            float chv = ch[col];
            #pragma unroll
            for (int r = 0; r < 4; ++r) {
                int row = rowbase + 4 * (lane >> 4) + r;
                if (row < N_NODES) {
                    float pz = az[nt][r] + czv;
                    float z = 1.0f / (1.0f + __expf(-pz));
                    float ph = ath[nt][r] + chv;
                    float t = __expf(-2.0f * fabsf(ph));
                    float th = (1.0f - t) / (1.0f + t);
                    th = copysignf(th, ph);
                    float h = Hf[(size_t)row * 128 + col];
                    out[(size_t)row * 128 + col] = z * h + (1.0f - z) * th;
                }
            }
        }
    }
}

// ---------------- launch ----------------

extern "C" void kernel_launch(void* const* d_in, const int* in_sizes, int n_in,
                              void* d_out, int out_size, void* d_ws, size_t ws_size,
                              hipStream_t stream) {
    const float*      X   = (const float*)d_in[0];
    const int*        EI  = (const int*)d_in[1];    // int32 from harness
    const float*      EW  = (const float*)d_in[2];
    const float*      Hf  = (const float*)d_in[3];
    const float*      Wz  = (const float*)d_in[4];
    const float*      bz  = (const float*)d_in[5];
    const float*      Wr  = (const float*)d_in[6];
    const float*      br  = (const float*)d_in[7];
    const float*      Wh  = (const float*)d_in[8];
    const float*      bh  = (const float*)d_in[9];
    const float*      Wlz = (const float*)d_in[10];
    const float*      blz = (const float*)d_in[11];
    const float*      Wlr = (const float*)d_in[12];
    const float*      blr = (const float*)d_in[13];
    const float*      Wlh = (const float*)d_in[14];
    const float*      blh = (const float*)d_in[15];
    float* out = (float*)d_out;

    char* p = (char*)d_ws;
    auto alloc = [&](size_t bytes) {
        char* r = p;
        p += (bytes + 255) & ~(size_t)255;
        return r;
    };
    float* deg    = (float*)alloc(M_PAD * 4);
    int*   counts = (int*)alloc(M_PAD * 4);
    int*   offs   = (int*)alloc((M_PAD + 1) * 4);
    int*   cursor = (int*)alloc(M_PAD * 4);
    float* dinv   = (float*)alloc(M_PAD * 4);
    float* dinv2  = (float*)alloc(M_PAD * 4);
    int*   partials = (int*)alloc(64 * 4);
    int*   blockoff = (int*)alloc(64 * 4);
    int2*  rec    = (int2*)alloc((size_t)N_EDGES * 8);
    unsigned short* Xb  = (unsigned short*)alloc((size_t)M_PAD * 128 * 2);
    unsigned short* Hb  = (unsigned short*)alloc((size_t)M_PAD * 128 * 2);
    unsigned short* Yb  = (unsigned short*)alloc((size_t)M_PAD * 128 * 2);
    float* Pf  = (float*)alloc(3 * 128 * 128 * 4);
    float* cgb = (float*)alloc(3 * 128 * 4);
    unsigned short* Wf2 = (unsigned short*)alloc(6 * 128 * 128 * 2);

    zero_kernel<<<(2 * M_PAD + 255) / 256, 256, 0, stream>>>((int*)deg, 2 * M_PAD);

    fuse_kernel<<<194, 256, 0, stream>>>(Wz, Wr, Wh, bz, br, bh,
                                         Wlz, Wlr, Wlh, blz, blr, blh, Pf, cgb);
    wfrag2_kernel<<<48, 256, 0, stream>>>(Pf, Wlz, Wlr, Wlh, Wf2);
    convert_kernel<<<6250, 256, 0, stream>>>(X, Hf, Xb, Hb);
    pass1_kernel<<<3125, 256, 0, stream>>>(EI, EW, deg, counts);
    node_kernel<<<196, 256, 0, stream>>>(deg, dinv, dinv2);
    scan1_kernel<<<SCAN_NBLK, 256, 0, stream>>>(counts, partials);
    scan2_kernel<<<1, 64, 0, stream>>>(partials, blockoff, offs);
    scan3_kernel<<<SCAN_NBLK, 256, 0, stream>>>(counts, blockoff, offs, cursor);
    fill_kernel<<<3125, 256, 0, stream>>>(EI, EW, dinv, cursor, rec);
    agg_kernel<<<12500, 256, 0, stream>>>(Xb, dinv2, offs, rec, Yb);
    gates2_kernel<<<NBLK2, 256, 0, stream>>>(Yb, Hb, Hf, Wf2, cgb, out);
}

// Round 5
// 236.392 us; speedup vs baseline: 2.0424x; 1.2043x over previous
//
#include <hip/hip_runtime.h>
#include <hip/hip_bf16.h>

#define N_NODES 50000
#define N_EDGES 800000
#define M_PAD   50048   // 391 * 128
#define SCAN_NBLK 49    // ceil(50000 / 1024)
#define NBLK2   782     // M_PAD / 64

typedef __attribute__((ext_vector_type(8))) short bf16x8_t;
typedef __attribute__((ext_vector_type(4))) float f32x4_t;

__device__ __forceinline__ unsigned short f2bf(float f) {
    unsigned u = __float_as_uint(f);
    u += 0x7FFFu + ((u >> 16) & 1u);
    return (unsigned short)(u >> 16);
}
__device__ __forceinline__ float bf2f(unsigned short h) {
    return __uint_as_float(((unsigned)h) << 16);
}

// ---------------- small prep kernels ----------------

__global__ void zero_kernel(int* p, int n) {
    int i = blockIdx.x * 256 + threadIdx.x;
    if (i < n) p[i] = 0;
}

__global__ void convert_kernel(const float* __restrict__ X, const float* __restrict__ Hsrc,
                               unsigned short* __restrict__ Xb, unsigned short* __restrict__ Hb) {
    int i = blockIdx.x * 256 + threadIdx.x;          // quad index
    if (i >= N_NODES * 32) return;
    float4 x = ((const float4*)X)[i];
    float4 h = ((const float4*)Hsrc)[i];
    ushort4 a, b;
    a.x = f2bf(x.x); a.y = f2bf(x.y); a.z = f2bf(x.z); a.w = f2bf(x.w);
    b.x = f2bf(h.x); b.y = f2bf(h.y); b.z = f2bf(h.z); b.w = f2bf(h.w);
    ((ushort4*)Xb)[i] = a;
    ((ushort4*)Hb)[i] = b;
}

// Fuse: P_g = W_g @ Wl_g[:128,:]  (f32), c_g = b_g @ Wl_g[:128,:] + bl_g
__global__ void fuse_kernel(const float* __restrict__ Wz, const float* __restrict__ Wr,
                            const float* __restrict__ Wh,
                            const float* __restrict__ bz, const float* __restrict__ br,
                            const float* __restrict__ bh,
                            const float* __restrict__ Wlz, const float* __restrict__ Wlr,
                            const float* __restrict__ Wlh,
                            const float* __restrict__ blz, const float* __restrict__ blr,
                            const float* __restrict__ blh,
                            float* __restrict__ Pf, float* __restrict__ cg) {
    int tid = blockIdx.x * 256 + threadIdx.x;
    if (tid < 3 * 16384) {
        int g = tid / 16384, k = (tid / 128) % 128, n = tid & 127;
        const float* W  = (g == 0) ? Wz  : (g == 1) ? Wr  : Wh;
        const float* Wl = (g == 0) ? Wlz : (g == 1) ? Wlr : Wlh;
        float acc = 0.f;
        #pragma unroll 8
        for (int j = 0; j < 128; ++j)
            acc = fmaf(W[k * 128 + j], Wl[j * 128 + n], acc);
        Pf[tid] = acc;
    } else if (tid < 3 * 16384 + 384) {
        int u = tid - 3 * 16384;
        int g = u / 128, n = u & 127;
        const float* b  = (g == 0) ? bz  : (g == 1) ? br  : bh;
        const float* Wl = (g == 0) ? Wlz : (g == 1) ? Wlr : Wlh;
        const float* bl = (g == 0) ? blz : (g == 1) ? blr : blh;
        float acc = bl[n];
        #pragma unroll 8
        for (int j = 0; j < 128; ++j)
            acc = fmaf(b[j], Wl[j * 128 + n], acc);
        cg[u] = acc;
    }
}

// Pack 6 K=128 matrices into MFMA B-fragment order (bf16).
// m=0..2: fused P_g (f32, from Pf); m=3..5: Wl_g[128:,:] (f32, from inputs).
// Frag element j of lane l at (nt,ks): src[ks*32+8*(l>>4)+j][nt*16+(l&15)]
__global__ void wfrag2_kernel(const float* __restrict__ Pf,
                              const float* __restrict__ Wlz, const float* __restrict__ Wlr,
                              const float* __restrict__ Wlh,
                              unsigned short* __restrict__ Wf2) {
    int tid = blockIdx.x * 256 + threadIdx.x;
    if (tid >= 6 * 2048) return;
    int m = tid / 2048, t = tid % 2048;
    int nt = t / 256, ks = (t / 64) % 4, lane = t % 64;
    const float* src;
    if (m < 3) src = Pf + m * 16384;
    else       src = ((m == 3) ? Wlz : (m == 4) ? Wlr : Wlh) + 128 * 128;
    unsigned short* dst = Wf2 + m * 16384 + ((nt * 4 + ks) * 64 + lane) * 8;
    int n = nt * 16 + (lane & 15);
    int k0 = ks * 32 + 8 * (lane >> 4);
    #pragma unroll
    for (int j = 0; j < 8; ++j) dst[j] = f2bf(src[(k0 + j) * 128 + n]);
}

// ---------------- graph prep ----------------

__global__ void pass1_kernel(const int* __restrict__ EI, const float* __restrict__ EW,
                             float* __restrict__ deg, int* __restrict__ counts) {
    int i = blockIdx.x * 256 + threadIdx.x;
    if (i >= N_EDGES) return;
    int t = EI[N_EDGES + i];
    atomicAdd(&deg[t], EW[i]);
    atomicAdd(&counts[t], 1);
}

// ---- hierarchical exclusive scan over counts (+ fused node dinv compute) ----

__global__ void scan1_kernel(const int* __restrict__ counts, const float* __restrict__ deg,
                             int* __restrict__ partials,
                             float* __restrict__ dinv, float* __restrict__ dinv2) {
    __shared__ int red[256];
    int t = threadIdx.x;
    int base = (blockIdx.x * 256 + t) * 4;
    int s = 0;
    #pragma unroll
    for (int i = 0; i < 4; ++i) {
        int idx = base + i;
        if (idx < N_NODES) {
            s += counts[idx];
            float d = deg[idx] + 1.0f;
            float di = rsqrtf(d);
            dinv[idx] = di;
            dinv2[idx] = di * di;
        }
    }
    red[t] = s;
    __syncthreads();
    #pragma unroll
    for (int off = 128; off > 0; off >>= 1) {
        if (t < off) red[t] += red[t + off];
        __syncthreads();
    }
    if (t == 0) partials[blockIdx.x] = red[0];
}

__global__ void scan2_kernel(const int* __restrict__ partials, int* __restrict__ blockoff,
                             int* __restrict__ offs) {
    int t = threadIdx.x;   // single wave of 64
    int orig = (t < SCAN_NBLK) ? partials[t] : 0;
    int v = orig;
    #pragma unroll
    for (int d = 1; d < 64; d <<= 1) {
        int u = __shfl_up(v, d, 64);
        if (t >= d) v += u;
    }
    if (t < SCAN_NBLK) blockoff[t] = v - orig;          // exclusive block offset
    if (t == SCAN_NBLK - 1) offs[N_NODES] = v;          // total edge count
}

__global__ void scan3_kernel(const int* __restrict__ counts, const int* __restrict__ blockoff,
                             int* __restrict__ offs, int* __restrict__ cursor) {
    __shared__ int sc[256];
    int t = threadIdx.x;
    int base = (blockIdx.x * 256 + t) * 4;
    int c[4];
    int s = 0;
    #pragma unroll
    for (int i = 0; i < 4; ++i) {
        int idx = base + i;
        c[i] = (idx < N_NODES) ? counts[idx] : 0;
        s += c[i];
    }
    sc[t] = s;
    __syncthreads();
    #pragma unroll
    for (int off = 1; off < 256; off <<= 1) {
        int v = (t >= off) ? sc[t - off] : 0;
        __syncthreads();
        sc[t] += v;
        __syncthreads();
    }
    int run = blockoff[blockIdx.x] + sc[t] - s;          // exclusive prefix
    #pragma unroll
    for (int i = 0; i < 4; ++i) {
        int idx = base + i;
        if (idx < N_NODES) { offs[idx] = run; cursor[idx] = run; run += c[i]; }
    }
}

__global__ void fill_kernel(const int* __restrict__ EI, const float* __restrict__ EW,
                            const float* __restrict__ dinv, int* __restrict__ cursor,
                            int2* __restrict__ rec) {
    int i = blockIdx.x * 256 + threadIdx.x;
    if (i >= N_EDGES) return;
    int s = EI[i];
    int t = EI[N_EDGES + i];
    float nw = dinv[s] * EW[i] * dinv[t];
    int pos = atomicAdd(&cursor[t], 1);
    rec[pos] = make_int2(s, __float_as_int(nw));
}

// ---------------- aggregation: Y = S*X + dinv2 .* X  (bf16 out) ----------------
// 1 wave per node; 4 lane-groups of 16 process 4 edges concurrently, each group
// gathering a full 256-B X row via dwordx4 (16 lanes x 16 B). rec prefetch
// software-pipelined. Cross-group reduce via 2x shfl_xor.

__global__ __launch_bounds__(256) void agg_kernel(const unsigned short* __restrict__ Xb,
                                                  const float* __restrict__ dinv2,
                                                  const int* __restrict__ offs,
                                                  const int2* __restrict__ rec,
                                                  unsigned short* __restrict__ Yb) {
    int node = blockIdx.x * 4 + (threadIdx.x >> 6);
    int lane = threadIdx.x & 63;
    if (node >= N_NODES) return;
    int grp = lane >> 4, lg = lane & 15;
    int e0 = offs[node], e1 = offs[node + 1];

    float acc[8];
    if (grp == 0) {
        float s = dinv2[node];
        bf16x8_t xv = *(const bf16x8_t*)(Xb + (size_t)node * 128 + lg * 8);
        #pragma unroll
        for (int j = 0; j < 8; ++j) acc[j] = s * bf2f((unsigned short)xv[j]);
    } else {
        #pragma unroll
        for (int j = 0; j < 8; ++j) acc[j] = 0.f;
    }

    int e = e0 + grp;
    int2 r;
    if (e < e1) r = rec[e];
    while (e < e1) {
        int2 cur = r;
        int en = e + 4;
        if (en < e1) r = rec[en];           // prefetch next record for this group
        float w = __int_as_float(cur.y);
        bf16x8_t xv = *(const bf16x8_t*)(Xb + (size_t)cur.x * 128 + lg * 8);
        #pragma unroll
        for (int j = 0; j < 8; ++j) acc[j] = fmaf(w, bf2f((unsigned short)xv[j]), acc[j]);
        e = en;
    }

    #pragma unroll
    for (int j = 0; j < 8; ++j) {
        float v = acc[j];
        v += __shfl_xor(v, 16, 64);
        v += __shfl_xor(v, 32, 64);
        acc[j] = v;
    }

    if (grp == 0) {
        ushort4 o0, o1;
        o0.x = f2bf(acc[0]); o0.y = f2bf(acc[1]); o0.z = f2bf(acc[2]); o0.w = f2bf(acc[3]);
        o1.x = f2bf(acc[4]); o1.y = f2bf(acc[5]); o1.z = f2bf(acc[6]); o1.w = f2bf(acc[7]);
        *(ushort4*)(Yb + (size_t)node * 128 + lg * 8) = o0;
        *(ushort4*)(Yb + (size_t)node * 128 + lg * 8 + 4) = o1;
    }
}

// ---------------- fused gates (weight-fused, 64 rows/block) ----------------
// Z  = sigmoid(Y@Az + H@Bz + cz)
// R  = sigmoid(Y@Ar + H@Br + cr)
// Ht = tanh   (Y@Ah + (H.R)@Bh + ch)
// out = Z.H + (1-Z).Ht

__global__ __launch_bounds__(256) void gates2_kernel(const unsigned short* __restrict__ Yb,
                                                     const unsigned short* __restrict__ Hb,
                                                     const float* __restrict__ Hf,
                                                     const unsigned short* __restrict__ Wf2,
                                                     const float* __restrict__ cg,
                                                     float* __restrict__ out) {
    __shared__ unsigned short rls[4][16][136];
    int wave = threadIdx.x >> 6, lane = threadIdx.x & 63;
    int rowbase = blockIdx.x * 64 + wave * 16;
    int rlo = lane & 15;
    int kg = 8 * (lane >> 4);
    int r0 = rowbase + rlo;

    const unsigned short* Az = Wf2;
    const unsigned short* Ar = Wf2 + 16384;
    const unsigned short* Ah = Wf2 + 2 * 16384;
    const unsigned short* Bz = Wf2 + 3 * 16384;
    const unsigned short* Br = Wf2 + 4 * 16384;
    const unsigned short* Bh = Wf2 + 5 * 16384;
    const float* cz = cg;
    const float* cr = cg + 128;
    const float* ch = cg + 256;

    // A-fragments for Y and H (live through both phases)
    bf16x8_t ay[4], ah[4];
    #pragma unroll
    for (int ks = 0; ks < 4; ++ks) {
        ay[ks] = *(const bf16x8_t*)(Yb + (size_t)r0 * 128 + ks * 32 + kg);
        ah[ks] = *(const bf16x8_t*)(Hb + (size_t)r0 * 128 + ks * 32 + kg);
    }

    // ---- phase R ----
    {
        f32x4_t acc[8];
        #pragma unroll
        for (int nt = 0; nt < 8; ++nt) acc[nt] = f32x4_t{0.f, 0.f, 0.f, 0.f};
        #pragma unroll
        for (int ks = 0; ks < 4; ++ks) {
            #pragma unroll
            for (int nt = 0; nt < 8; ++nt) {
                bf16x8_t b = *(const bf16x8_t*)(Ar + ((nt * 4 + ks) * 64 + lane) * 8);
                acc[nt] = __builtin_amdgcn_mfma_f32_16x16x32_bf16(ay[ks], b, acc[nt], 0, 0, 0);
            }
        }
        #pragma unroll
        for (int ks = 0; ks < 4; ++ks) {
            #pragma unroll
            for (int nt = 0; nt < 8; ++nt) {
                bf16x8_t b = *(const bf16x8_t*)(Br + ((nt * 4 + ks) * 64 + lane) * 8);
                acc[nt] = __builtin_amdgcn_mfma_f32_16x16x32_bf16(ah[ks], b, acc[nt], 0, 0, 0);
            }
        }
        #pragma unroll
        for (int nt = 0; nt < 8; ++nt) {
            int col = nt * 16 + rlo;
            float crv = cr[col];
            #pragma unroll
            for (int r = 0; r < 4; ++r) {
                float p = acc[nt][r] + crv;
                float rv = 1.0f / (1.0f + __expf(-p));
                rls[wave][4 * (lane >> 4) + r][col] = f2bf(rv);
            }
        }
        __syncthreads();
    }

    // ---- phase Z + H~ ----
    {
        f32x4_t az[8], ath[8];
        #pragma unroll
        for (int nt = 0; nt < 8; ++nt) {
            az[nt] = f32x4_t{0.f, 0.f, 0.f, 0.f};
            ath[nt] = f32x4_t{0.f, 0.f, 0.f, 0.f};
        }
        #pragma unroll
        for (int ks = 0; ks < 4; ++ks) {
            #pragma unroll
            for (int nt = 0; nt < 8; ++nt) {
                bf16x8_t bz_ = *(const bf16x8_t*)(Az + ((nt * 4 + ks) * 64 + lane) * 8);
                bf16x8_t bh_ = *(const bf16x8_t*)(Ah + ((nt * 4 + ks) * 64 + lane) * 8);
                az[nt]  = __builtin_amdgcn_mfma_f32_16x16x32_bf16(ay[ks], bz_, az[nt], 0, 0, 0);
                ath[nt] = __builtin_amdgcn_mfma_f32_16x16x32_bf16(ay[ks], bh_, ath[nt], 0, 0, 0);
            }
        }
        #pragma unroll
        for (int ks = 0; ks < 4; ++ks) {
            bf16x8_t rf = *(const bf16x8_t*)(&rls[wave][rlo][ks * 32 + kg]);
            bf16x8_t hr;
            #pragma unroll
            for (int j = 0; j < 8; ++j)
                hr[j] = (short)f2bf(bf2f((unsigned short)ah[ks][j]) * bf2f((unsigned short)rf[j]));
            #pragma unroll
            for (int nt = 0; nt < 8; ++nt) {
                bf16x8_t bz_ = *(const bf16x8_t*)(Bz + ((nt * 4 + ks) * 64 + lane) * 8);
                bf16x8_t bh_ = *(const bf16x8_t*)(Bh + ((nt * 4 + ks) * 64 + lane) * 8);
                az[nt]  = __builtin_amdgcn_mfma_f32_16x16x32_bf16(ah[ks], bz_, az[nt], 0, 0, 0);
                ath[nt] = __builtin_amdgcn_mfma_f32_16x16x32_bf16(hr, bh_, ath[nt], 0, 0, 0);
            }
        }
        #pragma unroll
        for (int nt = 0; nt < 8; ++nt) {
            int col = nt * 16 + rlo;
            float czv = cz[col];
            float chv = ch[col];
            #pragma unroll
            for (int r = 0; r < 4; ++r) {
                int row = rowbase + 4 * (lane >> 4) + r;
                if (row < N_NODES) {
                    float pz = az[nt][r] + czv;
                    float z = 1.0f / (1.0f + __expf(-pz));
                    float ph = ath[nt][r] + chv;
                    float t = __expf(-2.0f * fabsf(ph));
                    float th = (1.0f - t) / (1.0f + t);
                    th = copysignf(th, ph);
                    float h = Hf[(size_t)row * 128 + col];
                    out[(size_t)row * 128 + col] = z * h + (1.0f - z) * th;
                }
            }
        }
    }
}

// ---------------- launch ----------------

extern "C" void kernel_launch(void* const* d_in, const int* in_sizes, int n_in,
                              void* d_out, int out_size, void* d_ws, size_t ws_size,
                              hipStream_t stream) {
    const float*      X   = (const float*)d_in[0];
    const int*        EI  = (const int*)d_in[1];    // int32 from harness
    const float*      EW  = (const float*)d_in[2];
    const float*      Hf  = (const float*)d_in[3];
    const float*      Wz  = (const float*)d_in[4];
    const float*      bz  = (const float*)d_in[5];
    const float*      Wr  = (const float*)d_in[6];
    const float*      br  = (const float*)d_in[7];
    const float*      Wh  = (const float*)d_in[8];
    const float*      bh  = (const float*)d_in[9];
    const float*      Wlz = (const float*)d_in[10];
    const float*      blz = (const float*)d_in[11];
    const float*      Wlr = (const float*)d_in[12];
    const float*      blr = (const float*)d_in[13];
    const float*      Wlh = (const float*)d_in[14];
    const float*      blh = (const float*)d_in[15];
    float* out = (float*)d_out;

    char* p = (char*)d_ws;
    auto alloc = [&](size_t bytes) {
        char* r = p;
        p += (bytes + 255) & ~(size_t)255;
        return r;
    };
    float* deg    = (float*)alloc(M_PAD * 4);
    int*   counts = (int*)alloc(M_PAD * 4);
    int*   offs   = (int*)alloc((M_PAD + 1) * 4);
    int*   cursor = (int*)alloc(M_PAD * 4);
    float* dinv   = (float*)alloc(M_PAD * 4);
    float* dinv2  = (float*)alloc(M_PAD * 4);
    int*   partials = (int*)alloc(64 * 4);
    int*   blockoff = (int*)alloc(64 * 4);
    int2*  rec    = (int2*)alloc((size_t)N_EDGES * 8);
    unsigned short* Xb  = (unsigned short*)alloc((size_t)M_PAD * 128 * 2);
    unsigned short* Hb  = (unsigned short*)alloc((size_t)M_PAD * 128 * 2);
    unsigned short* Yb  = (unsigned short*)alloc((size_t)M_PAD * 128 * 2);
    float* Pf  = (float*)alloc(3 * 128 * 128 * 4);
    float* cgb = (float*)alloc(3 * 128 * 4);
    unsigned short* Wf2 = (unsigned short*)alloc(6 * 128 * 128 * 2);

    zero_kernel<<<(2 * M_PAD + 255) / 256, 256, 0, stream>>>((int*)deg, 2 * M_PAD);

    fuse_kernel<<<194, 256, 0, stream>>>(Wz, Wr, Wh, bz, br, bh,
                                         Wlz, Wlr, Wlh, blz, blr, blh, Pf, cgb);
    wfrag2_kernel<<<48, 256, 0, stream>>>(Pf, Wlz, Wlr, Wlh, Wf2);
    convert_kernel<<<6250, 256, 0, stream>>>(X, Hf, Xb, Hb);
    pass1_kernel<<<3125, 256, 0, stream>>>(EI, EW, deg, counts);
    scan1_kernel<<<SCAN_NBLK, 256, 0, stream>>>(counts, deg, partials, dinv, dinv2);
    scan2_kernel<<<1, 64, 0, stream>>>(partials, blockoff, offs);
    scan3_kernel<<<SCAN_NBLK, 256, 0, stream>>>(counts, blockoff, offs, cursor);
    fill_kernel<<<3125, 256, 0, stream>>>(EI, EW, dinv, cursor, rec);
    agg_kernel<<<12500, 256, 0, stream>>>(Xb, dinv2, offs, rec, Yb);
    gates2_kernel<<<NBLK2, 256, 0, stream>>>(Yb, Hb, Hf, Wf2, cgb, out);
}

// Round 6
// 176.993 us; speedup vs baseline: 2.7278x; 1.3356x over previous
//
#include <hip/hip_runtime.h>
#include <hip/hip_bf16.h>

#define N_NODES 50000
#define N_EDGES 800000
#define M_PAD   50048   // 391 * 128
#define SCAN_NBLK 49    // ceil(50000 / 1024)
#define NBLK2   782     // M_PAD / 64

typedef __attribute__((ext_vector_type(8))) short bf16x8_t;
typedef __attribute__((ext_vector_type(4))) float f32x4_t;

__device__ __forceinline__ unsigned short f2bf(float f) {
    unsigned u = __float_as_uint(f);
    u += 0x7FFFu + ((u >> 16) & 1u);
    return (unsigned short)(u >> 16);
}
__device__ __forceinline__ float bf2f(unsigned short h) {
    return __uint_as_float(((unsigned)h) << 16);
}

// ---------------- small prep kernels ----------------

__global__ void zero_kernel(int* p, int n) {
    int i = blockIdx.x * 256 + threadIdx.x;
    if (i < n) p[i] = 0;
}

__global__ void convert_kernel(const float* __restrict__ X, const float* __restrict__ Hsrc,
                               unsigned short* __restrict__ Xb, unsigned short* __restrict__ Hb) {
    int i = blockIdx.x * 256 + threadIdx.x;          // quad index
    if (i >= N_NODES * 32) return;
    float4 x = ((const float4*)X)[i];
    float4 h = ((const float4*)Hsrc)[i];
    ushort4 a, b;
    a.x = f2bf(x.x); a.y = f2bf(x.y); a.z = f2bf(x.z); a.w = f2bf(x.w);
    b.x = f2bf(h.x); b.y = f2bf(h.y); b.z = f2bf(h.z); b.w = f2bf(h.w);
    ((ushort4*)Xb)[i] = a;
    ((ushort4*)Hb)[i] = b;
}

// Fuse: P_g = W_g @ Wl_g[:128,:]  (f32), c_g = b_g @ Wl_g[:128,:] + bl_g
__global__ void fuse_kernel(const float* __restrict__ Wz, const float* __restrict__ Wr,
                            const float* __restrict__ Wh,
                            const float* __restrict__ bz, const float* __restrict__ br,
                            const float* __restrict__ bh,
                            const float* __restrict__ Wlz, const float* __restrict__ Wlr,
                            const float* __restrict__ Wlh,
                            const float* __restrict__ blz, const float* __restrict__ blr,
                            const float* __restrict__ blh,
                            float* __restrict__ Pf, float* __restrict__ cg) {
    int tid = blockIdx.x * 256 + threadIdx.x;
    if (tid < 3 * 16384) {
        int g = tid / 16384, k = (tid / 128) % 128, n = tid & 127;
        const float* W  = (g == 0) ? Wz  : (g == 1) ? Wr  : Wh;
        const float* Wl = (g == 0) ? Wlz : (g == 1) ? Wlr : Wlh;
        float acc = 0.f;
        #pragma unroll 8
        for (int j = 0; j < 128; ++j)
            acc = fmaf(W[k * 128 + j], Wl[j * 128 + n], acc);
        Pf[tid] = acc;
    } else if (tid < 3 * 16384 + 384) {
        int u = tid - 3 * 16384;
        int g = u / 128, n = u & 127;
        const float* b  = (g == 0) ? bz  : (g == 1) ? br  : bh;
        const float* Wl = (g == 0) ? Wlz : (g == 1) ? Wlr : Wlh;
        const float* bl = (g == 0) ? blz : (g == 1) ? blr : blh;
        float acc = bl[n];
        #pragma unroll 8
        for (int j = 0; j < 128; ++j)
            acc = fmaf(b[j], Wl[j * 128 + n], acc);
        cg[u] = acc;
    }
}

// Pack 6 K=128 matrices into MFMA B-fragment order (bf16).
__global__ void wfrag2_kernel(const float* __restrict__ Pf,
                              const float* __restrict__ Wlz, const float* __restrict__ Wlr,
                              const float* __restrict__ Wlh,
                              unsigned short* __restrict__ Wf2) {
    int tid = blockIdx.x * 256 + threadIdx.x;
    if (tid >= 6 * 2048) return;
    int m = tid / 2048, t = tid % 2048;
    int nt = t / 256, ks = (t / 64) % 4, lane = t % 64;
    const float* src;
    if (m < 3) src = Pf + m * 16384;
    else       src = ((m == 3) ? Wlz : (m == 4) ? Wlr : Wlh) + 128 * 128;
    unsigned short* dst = Wf2 + m * 16384 + ((nt * 4 + ks) * 64 + lane) * 8;
    int n = nt * 16 + (lane & 15);
    int k0 = ks * 32 + 8 * (lane >> 4);
    #pragma unroll
    for (int j = 0; j < 8; ++j) dst[j] = f2bf(src[(k0 + j) * 128 + n]);
}

// ---------------- graph prep ----------------

// One atomic per edge: count AND per-edge rank (returned old value).
__global__ void pass1_kernel(const int* __restrict__ EI, int* __restrict__ counts,
                             int* __restrict__ rank) {
    int i = blockIdx.x * 256 + threadIdx.x;
    if (i >= N_EDGES) return;
    int t = EI[N_EDGES + i];
    rank[i] = atomicAdd(&counts[t], 1);
}

// ---- hierarchical exclusive scan over counts ----

__global__ void scan1_kernel(const int* __restrict__ counts, int* __restrict__ partials) {
    __shared__ int red[256];
    int t = threadIdx.x;
    int base = (blockIdx.x * 256 + t) * 4;
    int s = 0;
    #pragma unroll
    for (int i = 0; i < 4; ++i) {
        int idx = base + i;
        if (idx < N_NODES) s += counts[idx];
    }
    red[t] = s;
    __syncthreads();
    #pragma unroll
    for (int off = 128; off > 0; off >>= 1) {
        if (t < off) red[t] += red[t + off];
        __syncthreads();
    }
    if (t == 0) partials[blockIdx.x] = red[0];
}

__global__ void scan2_kernel(const int* __restrict__ partials, int* __restrict__ blockoff,
                             int* __restrict__ offs) {
    int t = threadIdx.x;   // single wave of 64
    int orig = (t < SCAN_NBLK) ? partials[t] : 0;
    int v = orig;
    #pragma unroll
    for (int d = 1; d < 64; d <<= 1) {
        int u = __shfl_up(v, d, 64);
        if (t >= d) v += u;
    }
    if (t < SCAN_NBLK) blockoff[t] = v - orig;          // exclusive block offset
    if (t == SCAN_NBLK - 1) offs[N_NODES] = v;          // total edge count
}

__global__ void scan3_kernel(const int* __restrict__ counts, const int* __restrict__ blockoff,
                             int* __restrict__ offs) {
    __shared__ int sc[256];
    int t = threadIdx.x;
    int base = (blockIdx.x * 256 + t) * 4;
    int c[4];
    int s = 0;
    #pragma unroll
    for (int i = 0; i < 4; ++i) {
        int idx = base + i;
        c[i] = (idx < N_NODES) ? counts[idx] : 0;
        s += c[i];
    }
    sc[t] = s;
    __syncthreads();
    #pragma unroll
    for (int off = 1; off < 256; off <<= 1) {
        int v = (t >= off) ? sc[t - off] : 0;
        __syncthreads();
        sc[t] += v;
        __syncthreads();
    }
    int run = blockoff[blockIdx.x] + sc[t] - s;          // exclusive prefix
    #pragma unroll
    for (int i = 0; i < 4; ++i) {
        int idx = base + i;
        if (idx < N_NODES) { offs[idx] = run; run += c[i]; }
    }
}

// Atomic-free fill: position = offs[t] + rank[i]; store RAW weight.
__global__ void fill_kernel(const int* __restrict__ EI, const float* __restrict__ EW,
                            const int* __restrict__ offs, const int* __restrict__ rank,
                            int2* __restrict__ rec) {
    int i = blockIdx.x * 256 + threadIdx.x;
    if (i >= N_EDGES) return;
    int s = EI[i];
    int t = EI[N_EDGES + i];
    rec[offs[t] + rank[i]] = make_int2(s, __float_as_int(EW[i]));
}

// Per-node degree from raw weights in own CSR range (no atomics), then dinv.
__global__ void deg_kernel(const int* __restrict__ offs, const int2* __restrict__ rec,
                           float* __restrict__ dinv, float* __restrict__ dinv2) {
    int n = blockIdx.x * 256 + threadIdx.x;
    if (n >= N_NODES) return;
    int e0 = offs[n], e1 = offs[n + 1];
    float d = 1.0f;                 // self-loop weight
    #pragma unroll 4
    for (int e = e0; e < e1; ++e) d += __int_as_float(rec[e].y);
    float di = rsqrtf(d);
    dinv[n] = di;
    dinv2[n] = di * di;
}

// ---------------- aggregation: Y = dinv_t * (S_raw*X) + dinv2_t * X  (bf16 out) --
// 1 wave per node; 4 lane-groups of 16 process 4 edges concurrently, each group
// gathering a full 256-B X row via dwordx4. Edge weight normalized in-flight by
// dinv[s]; dinv[t] applied once after cross-group reduce.

__global__ __launch_bounds__(256) void agg_kernel(const unsigned short* __restrict__ Xb,
                                                  const float* __restrict__ dinv,
                                                  const float* __restrict__ dinv2,
                                                  const int* __restrict__ offs,
                                                  const int2* __restrict__ rec,
                                                  unsigned short* __restrict__ Yb) {
    int node = blockIdx.x * 4 + (threadIdx.x >> 6);
    int lane = threadIdx.x & 63;
    if (node >= N_NODES) return;
    int grp = lane >> 4, lg = lane & 15;
    int e0 = offs[node], e1 = offs[node + 1];

    float acc[8];
    #pragma unroll
    for (int j = 0; j < 8; ++j) acc[j] = 0.f;

    bf16x8_t xs;
    if (grp == 0) xs = *(const bf16x8_t*)(Xb + (size_t)node * 128 + lg * 8);

    int e = e0 + grp;
    int2 r;
    if (e < e1) r = rec[e];
    while (e < e1) {
        int2 cur = r;
        int en = e + 4;
        if (en < e1) r = rec[en];           // prefetch next record for this group
        float w = __int_as_float(cur.y) * dinv[cur.x];
        bf16x8_t xv = *(const bf16x8_t*)(Xb + (size_t)cur.x * 128 + lg * 8);
        #pragma unroll
        for (int j = 0; j < 8; ++j) acc[j] = fmaf(w, bf2f((unsigned short)xv[j]), acc[j]);
        e = en;
    }

    #pragma unroll
    for (int j = 0; j < 8; ++j) {
        float v = acc[j];
        v += __shfl_xor(v, 16, 64);
        v += __shfl_xor(v, 32, 64);
        acc[j] = v;
    }

    if (grp == 0) {
        float dt = dinv[node], dt2 = dinv2[node];
        ushort4 o0, o1;
        o0.x = f2bf(dt * acc[0] + dt2 * bf2f((unsigned short)xs[0]));
        o0.y = f2bf(dt * acc[1] + dt2 * bf2f((unsigned short)xs[1]));
        o0.z = f2bf(dt * acc[2] + dt2 * bf2f((unsigned short)xs[2]));
        o0.w = f2bf(dt * acc[3] + dt2 * bf2f((unsigned short)xs[3]));
        o1.x = f2bf(dt * acc[4] + dt2 * bf2f((unsigned short)xs[4]));
        o1.y = f2bf(dt * acc[5] + dt2 * bf2f((unsigned short)xs[5]));
        o1.z = f2bf(dt * acc[6] + dt2 * bf2f((unsigned short)xs[6]));
        o1.w = f2bf(dt * acc[7] + dt2 * bf2f((unsigned short)xs[7]));
        *(ushort4*)(Yb + (size_t)node * 128 + lg * 8) = o0;
        *(ushort4*)(Yb + (size_t)node * 128 + lg * 8 + 4) = o1;
    }
}

// ---------------- fused gates (weight-fused, 64 rows/block) ----------------
// Z  = sigmoid(Y@Az + H@Bz + cz)
// R  = sigmoid(Y@Ar + H@Br + cr)
// Ht = tanh   (Y@Ah + (H.R)@Bh + ch)
// out = Z.H + (1-Z).Ht

__global__ __launch_bounds__(256) void gates2_kernel(const unsigned short* __restrict__ Yb,
                                                     const unsigned short* __restrict__ Hb,
                                                     const float* __restrict__ Hf,
                                                     const unsigned short* __restrict__ Wf2,
                                                     const float* __restrict__ cg,
                                                     float* __restrict__ out) {
    __shared__ unsigned short rls[4][16][136];
    int wave = threadIdx.x >> 6, lane = threadIdx.x & 63;
    int rowbase = blockIdx.x * 64 + wave * 16;
    int rlo = lane & 15;
    int kg = 8 * (lane >> 4);
    int r0 = rowbase + rlo;

    const unsigned short* Az = Wf2;
    const unsigned short* Ar = Wf2 + 16384;
    const unsigned short* Ah = Wf2 + 2 * 16384;
    const unsigned short* Bz = Wf2 + 3 * 16384;
    const unsigned short* Br = Wf2 + 4 * 16384;
    const unsigned short* Bh = Wf2 + 5 * 16384;
    const float* cz = cg;
    const float* cr = cg + 128;
    const float* ch = cg + 256;

    // A-fragments for Y and H (live through both phases)
    bf16x8_t ay[4], ah[4];
    #pragma unroll
    for (int ks = 0; ks < 4; ++ks) {
        ay[ks] = *(const bf16x8_t*)(Yb + (size_t)r0 * 128 + ks * 32 + kg);
        ah[ks] = *(const bf16x8_t*)(Hb + (size_t)r0 * 128 + ks * 32 + kg);
    }

    // ---- phase R ----
    {
        f32x4_t acc[8];
        #pragma unroll
        for (int nt = 0; nt < 8; ++nt) acc[nt] = f32x4_t{0.f, 0.f, 0.f, 0.f};
        #pragma unroll
        for (int ks = 0; ks < 4; ++ks) {
            #pragma unroll
            for (int nt = 0; nt < 8; ++nt) {
                bf16x8_t b = *(const bf16x8_t*)(Ar + ((nt * 4 + ks) * 64 + lane) * 8);
                acc[nt] = __builtin_amdgcn_mfma_f32_16x16x32_bf16(ay[ks], b, acc[nt], 0, 0, 0);
            }
        }
        #pragma unroll
        for (int ks = 0; ks < 4; ++ks) {
            #pragma unroll
            for (int nt = 0; nt < 8; ++nt) {
                bf16x8_t b = *(const bf16x8_t*)(Br + ((nt * 4 + ks) * 64 + lane) * 8);
                acc[nt] = __builtin_amdgcn_mfma_f32_16x16x32_bf16(ah[ks], b, acc[nt], 0, 0, 0);
            }
        }
        #pragma unroll
        for (int nt = 0; nt < 8; ++nt) {
            int col = nt * 16 + rlo;
            float crv = cr[col];
            #pragma unroll
            for (int r = 0; r < 4; ++r) {
                float p = acc[nt][r] + crv;
                float rv = 1.0f / (1.0f + __expf(-p));
                rls[wave][4 * (lane >> 4) + r][col] = f2bf(rv);
            }
        }
        __syncthreads();
    }

    // ---- phase Z + H~ ----
    {
        f32x4_t az[8], ath[8];
        #pragma unroll
        for (int nt = 0; nt < 8; ++nt) {
            az[nt] = f32x4_t{0.f, 0.f, 0.f, 0.f};
            ath[nt] = f32x4_t{0.f, 0.f, 0.f, 0.f};
        }
        #pragma unroll
        for (int ks = 0; ks < 4; ++ks) {
            #pragma unroll
            for (int nt = 0; nt < 8; ++nt) {
                bf16x8_t bz_ = *(const bf16x8_t*)(Az + ((nt * 4 + ks) * 64 + lane) * 8);
                bf16x8_t bh_ = *(const bf16x8_t*)(Ah + ((nt * 4 + ks) * 64 + lane) * 8);
                az[nt]  = __builtin_amdgcn_mfma_f32_16x16x32_bf16(ay[ks], bz_, az[nt], 0, 0, 0);
                ath[nt] = __builtin_amdgcn_mfma_f32_16x16x32_bf16(ay[ks], bh_, ath[nt], 0, 0, 0);
            }
        }
        #pragma unroll
        for (int ks = 0; ks < 4; ++ks) {
            bf16x8_t rf = *(const bf16x8_t*)(&rls[wave][rlo][ks * 32 + kg]);
            bf16x8_t hr;
            #pragma unroll
            for (int j = 0; j < 8; ++j)
                hr[j] = (short)f2bf(bf2f((unsigned short)ah[ks][j]) * bf2f((unsigned short)rf[j]));
            #pragma unroll
            for (int nt = 0; nt < 8; ++nt) {
                bf16x8_t bz_ = *(const bf16x8_t*)(Bz + ((nt * 4 + ks) * 64 + lane) * 8);
                bf16x8_t bh_ = *(const bf16x8_t*)(Bh + ((nt * 4 + ks) * 64 + lane) * 8);
                az[nt]  = __builtin_amdgcn_mfma_f32_16x16x32_bf16(ah[ks], bz_, az[nt], 0, 0, 0);
                ath[nt] = __builtin_amdgcn_mfma_f32_16x16x32_bf16(hr, bh_, ath[nt], 0, 0, 0);
            }
        }
        #pragma unroll
        for (int nt = 0; nt < 8; ++nt) {
            int col = nt * 16 + rlo;
            float czv = cz[col];
            float chv = ch[col];
            #pragma unroll
            for (int r = 0; r < 4; ++r) {
                int row = rowbase + 4 * (lane >> 4) + r;
                if (row < N_NODES) {
                    float pz = az[nt][r] + czv;
                    float z = 1.0f / (1.0f + __expf(-pz));
                    float ph = ath[nt][r] + chv;
                    float t = __expf(-2.0f * fabsf(ph));
                    float th = (1.0f - t) / (1.0f + t);
                    th = copysignf(th, ph);
                    float h = Hf[(size_t)row * 128 + col];
                    out[(size_t)row * 128 + col] = z * h + (1.0f - z) * th;
                }
            }
        }
    }
}

// ---------------- launch ----------------

extern "C" void kernel_launch(void* const* d_in, const int* in_sizes, int n_in,
                              void* d_out, int out_size, void* d_ws, size_t ws_size,
                              hipStream_t stream) {
    const float*      X   = (const float*)d_in[0];
    const int*        EI  = (const int*)d_in[1];    // int32 from harness
    const float*      EW  = (const float*)d_in[2];
    const float*      Hf  = (const float*)d_in[3];
    const float*      Wz  = (const float*)d_in[4];
    const float*      bz  = (const float*)d_in[5];
    const float*      Wr  = (const float*)d_in[6];
    const float*      br  = (const float*)d_in[7];
    const float*      Wh  = (const float*)d_in[8];
    const float*      bh  = (const float*)d_in[9];
    const float*      Wlz = (const float*)d_in[10];
    const float*      blz = (const float*)d_in[11];
    const float*      Wlr = (const float*)d_in[12];
    const float*      blr = (const float*)d_in[13];
    const float*      Wlh = (const float*)d_in[14];
    const float*      blh = (const float*)d_in[15];
    float* out = (float*)d_out;

    char* p = (char*)d_ws;
    auto alloc = [&](size_t bytes) {
        char* r = p;
        p += (bytes + 255) & ~(size_t)255;
        return r;
    };
    int*   counts = (int*)alloc(M_PAD * 4);
    int*   offs   = (int*)alloc((M_PAD + 1) * 4);
    float* dinv   = (float*)alloc(M_PAD * 4);
    float* dinv2  = (float*)alloc(M_PAD * 4);
    int*   partials = (int*)alloc(64 * 4);
    int*   blockoff = (int*)alloc(64 * 4);
    int*   rank   = (int*)alloc((size_t)N_EDGES * 4);
    int2*  rec    = (int2*)alloc((size_t)N_EDGES * 8);
    unsigned short* Xb  = (unsigned short*)alloc((size_t)M_PAD * 128 * 2);
    unsigned short* Hb  = (unsigned short*)alloc((size_t)M_PAD * 128 * 2);
    unsigned short* Yb  = (unsigned short*)alloc((size_t)M_PAD * 128 * 2);
    float* Pf  = (float*)alloc(3 * 128 * 128 * 4);
    float* cgb = (float*)alloc(3 * 128 * 4);
    unsigned short* Wf2 = (unsigned short*)alloc(6 * 128 * 128 * 2);

    zero_kernel<<<(M_PAD + 255) / 256, 256, 0, stream>>>(counts, M_PAD);

    fuse_kernel<<<194, 256, 0, stream>>>(Wz, Wr, Wh, bz, br, bh,
                                         Wlz, Wlr, Wlh, blz, blr, blh, Pf, cgb);
    wfrag2_kernel<<<48, 256, 0, stream>>>(Pf, Wlz, Wlr, Wlh, Wf2);
    convert_kernel<<<6250, 256, 0, stream>>>(X, Hf, Xb, Hb);
    pass1_kernel<<<3125, 256, 0, stream>>>(EI, counts, rank);
    scan1_kernel<<<SCAN_NBLK, 256, 0, stream>>>(counts, partials);
    scan2_kernel<<<1, 64, 0, stream>>>(partials, blockoff, offs);
    scan3_kernel<<<SCAN_NBLK, 256, 0, stream>>>(counts, blockoff, offs);
    fill_kernel<<<3125, 256, 0, stream>>>(EI, EW, offs, rank, rec);
    deg_kernel<<<196, 256, 0, stream>>>(offs, rec, dinv, dinv2);
    agg_kernel<<<12500, 256, 0, stream>>>(Xb, dinv, dinv2, offs, rec, Yb);
    gates2_kernel<<<NBLK2, 256, 0, stream>>>(Yb, Hb, Hf, Wf2, cgb, out);
}